// Round 6
// baseline (945.351 us; speedup 1.0000x reference)
//
#include <hip/hip_runtime.h>
#include <hip/hip_bf16.h>

#define ND 30000
#define NT 15000
#define FD 200
#define FT 570
#define HDIM 768
#define EDD 300000
#define EDT 400000
#define ETT 200000

#define KPD 256   // FD padded to x64 (gather rel1 row: 512B)
#define KPT 576   // FT padded to x64 (gather rel2 row: 1152B)
#define KPA 832   // agg K = KPD + KPT (concat), GEMM K dim

#define BM 128
#define BN 128
#define GBK 32
#define KTILES (KPA / GBK)         // 26
#define MTD ((ND + BM - 1) / BM)   // 235
#define MTT ((NT + BM - 1) / BM)   // 118

typedef __attribute__((ext_vector_type(8))) short short8;
typedef __attribute__((ext_vector_type(4))) float float4v;

// ---------------- dtype-adaptive load/store ----------------
// flag[0]: 0 = harness float tensors are bf16, 1 = fp32.

__device__ __forceinline__ float ldx(const void* p, size_t i, int f32) {
  return f32 ? ((const float*)p)[i]
             : __bfloat162float(((const __hip_bfloat16*)p)[i]);
}
__device__ __forceinline__ void stx(void* p, size_t i, int f32, float v) {
  if (f32) ((float*)p)[i] = v;
  else     ((__hip_bfloat16*)p)[i] = __float2bfloat16(v);
}
__device__ __forceinline__ float b2f(unsigned short u) {
  return __uint_as_float(((unsigned)u) << 16);
}
__device__ __forceinline__ unsigned short f2b(float f) {
  __hip_bfloat16 h = __float2bfloat16(f);
  return *(unsigned short*)&h;
}
__device__ __forceinline__ unsigned pk2(float a, float b) {
  return (unsigned)f2b(a) | ((unsigned)f2b(b) << 16);
}

__device__ __forceinline__ float wave_reduce(float v) {
#pragma unroll
  for (int off = 32; off > 0; off >>= 1) v += __shfl_xor(v, off, 64);
  return v;
}

// ---------------- dtype sniffer ----------------
__global__ void sniff(const void* x, int* flag) {
  int t = threadIdx.x;
  float cnt = 0.f;
  for (int i = t; i < 8192; i += 256) {
    float v = __bfloat162float(((const __hip_bfloat16*)x)[i]);
    if (!(fabsf(v) < 100.f)) cnt += 1.f;  // true for NaN too
  }
  cnt = wave_reduce(cnt);
  __shared__ float red[4];
  if ((t & 63) == 0) red[t >> 6] = cnt;
  __syncthreads();
  if (t == 0) flag[0] = (red[0] + red[1] + red[2] + red[3] > 256.f) ? 1 : 0;
}

// -------- all 8 va vectors in one launch: va[k] = sum_h W[k,h]*a[h] --------
__global__ __launch_bounds__(256) void wa_dot8(
    const void* W0, const void* W1, const void* W2, const void* W3,
    const void* W4, const void* W5, const void* W6, const void* W7,
    const void* a0, const void* a1, const void* a2, const void* a3,
    const void* a4, const void* a5, const void* a6, const void* a7,
    float* __restrict__ vaD, float* __restrict__ vaT,
    const int* __restrict__ flag) {
  const void* Ws[8] = {W0, W1, W2, W3, W4, W5, W6, W7};
  const void* as[8] = {a0, a1, a2, a3, a4, a5, a6, a7};
  int f32 = flag[0];
  int wid = (blockIdx.x * 256 + threadIdx.x) >> 6;
  int lane = threadIdx.x & 63;
  const void* W; const void* a; float* out; int k;
  if (wid < 4 * FD) {
    int q = wid / FD; k = wid - q * FD;
    W = Ws[q]; a = as[q]; out = vaD + q * FD + k;
  } else {
    int w2 = wid - 4 * FD;
    if (w2 >= 4 * FT) return;
    int q = w2 / FT; k = w2 - q * FT;
    W = Ws[4 + q]; a = as[4 + q]; out = vaT + q * FT + k;
  }
  float acc = 0.f;
  for (int h = lane; h < HDIM; h += 64)
    acc += ldx(W, (size_t)k * HDIM + h, f32) * ldx(a, h, f32);
  acc = wave_reduce(acc);
  if (lane == 0) *out = acc;
}

// -------- token-dot scalars: ts layout {D0,D1,T0,D2, D3,T1,T2,T3} --------
__global__ void tok_dots(const void* __restrict__ tok1, const void* __restrict__ tok2,
                         const float* __restrict__ vaD, const float* __restrict__ vaT,
                         float* __restrict__ ts, const int* __restrict__ flag) {
  int w = threadIdx.x >> 6;   // 0..7 (512 threads)
  int lane = threadIdx.x & 63;
  int f32 = flag[0];
  float acc = 0.f;
  if (w < 4) {
    for (int k = lane; k < FD; k += 64) acc += ldx(tok1, k, f32) * vaD[w * FD + k];
  } else {
    int q = w - 4;
    for (int k = lane; k < FT; k += 64) acc += ldx(tok2, k, f32) * vaT[q * FT + k];
  }
  acc = wave_reduce(acc);
  if (lane == 0) {
    const int map[8] = {0, 1, 3, 4, 2, 5, 6, 7};  // w -> ts slot
    ts[map[w]] = acc;
  }
}

// ------ fused pack (x -> bf16 padded) + 4 row dots, both node types ------
__global__ __launch_bounds__(256) void pack_rowdot(
    const void* __restrict__ xD, const void* __restrict__ xT,
    const float* __restrict__ vaD, const float* __restrict__ vaT,
    unsigned short* __restrict__ Ad, unsigned short* __restrict__ At,
    float* __restrict__ dvec, float* __restrict__ tvec,
    const int* __restrict__ flag) {
  int wid = (blockIdx.x * 256 + threadIdx.x) >> 6;
  int lane = threadIdx.x & 63;
  int f32 = flag[0];
  const void* x; const float* va; unsigned short* Aout; float* outv; int K, Kp, row;
  if (wid < ND) { x = xD; va = vaD; Aout = Ad; outv = dvec; K = FD; Kp = KPD; row = wid; }
  else if (wid < ND + NT) { x = xT; va = vaT; Aout = At; outv = tvec; K = FT; Kp = KPT; row = wid - ND; }
  else return;
  float a0 = 0.f, a1 = 0.f, a2 = 0.f, a3 = 0.f;
  for (int it = 0; it * 256 < Kp; ++it) {
    int base = 4 * lane + it * 256;
    if (base >= Kp) continue;
    ushort4 o;
    unsigned short r[4];
    float fv[4];
#pragma unroll
    for (int c = 0; c < 4; ++c) {
      int kk = base + c;
      float f = (kk < K) ? ldx(x, (size_t)row * K + kk, f32) : 0.f;
      fv[c] = f;
      r[c] = f2b(f);
    }
    o.x = r[0]; o.y = r[1]; o.z = r[2]; o.w = r[3];
    *(ushort4*)(Aout + (size_t)row * Kp + base) = o;
#pragma unroll
    for (int c = 0; c < 4; ++c) {
      int kk = base + c;
      if (kk < K) {
        a0 += fv[c] * va[kk];
        a1 += fv[c] * va[K + kk];
        a2 += fv[c] * va[2 * K + kk];
        a3 += fv[c] * va[3 * K + kk];
      }
    }
  }
  a0 = wave_reduce(a0); a1 = wave_reduce(a1);
  a2 = wave_reduce(a2); a3 = wave_reduce(a3);
  if (lane == 0) {
    float* o = outv + (size_t)row * 4;
    o[0] = a0; o[1] = a1; o[2] = a2; o[3] = a3;
  }
}

// ------ pack both concat B^T [768][832] in one launch ------
__global__ __launch_bounds__(256) void pack_bTa2(
    const void* __restrict__ W1a, const void* __restrict__ W2a, unsigned short* __restrict__ Ba,
    const void* __restrict__ W1b, const void* __restrict__ W2b, unsigned short* __restrict__ Bb,
    const int* __restrict__ flag) {
  int f32 = flag[0];
  long long one = (long long)HDIM * KPA / 4;
  long long gid = (long long)blockIdx.x * 256 + threadIdx.x;
  if (gid >= 2 * one) return;
  const void* W1; const void* W2; unsigned short* Bout;
  if (gid < one) { W1 = W1a; W2 = W2a; Bout = Ba; }
  else { W1 = W1b; W2 = W2b; Bout = Bb; gid -= one; }
  long long e0 = gid * 4;
  int n = (int)(e0 / KPA);
  int k = (int)(e0 % KPA);
  ushort4 o;
  unsigned short r[4];
#pragma unroll
  for (int c = 0; c < 4; ++c) {
    int kk = k + c;
    float f = 0.f;
    if (kk < 256) {
      if (kk < FD) f = ldx(W1, (size_t)kk * HDIM + n, f32);
    } else {
      int k2 = kk - 256;
      if (k2 < FT) f = ldx(W2, (size_t)k2 * HDIM + n, f32);
    }
    r[c] = f2b(f);
  }
  o.x = r[0]; o.y = r[1]; o.z = r[2]; o.w = r[3];
  *(ushort4*)(Bout + e0) = o;
}

// ---------------- batched graph-prep kernels ----------------
__global__ void zero_i32(int* __restrict__ p, int n) {
  int i = blockIdx.x * 256 + threadIdx.x;
  if (i < n) p[i] = 0;
}

__global__ void count4(const int* __restrict__ dd_dst, const int* __restrict__ dt_src,
                       const int* __restrict__ dt_dst, const int* __restrict__ tt_dst,
                       int* __restrict__ c_dd, int* __restrict__ c_rv,
                       int* __restrict__ c_dt, int* __restrict__ c_tt) {
  int i = blockIdx.x * 256 + threadIdx.x;
  if (i < EDD + ND) { int d = (i < EDD) ? dd_dst[i] : i - EDD; atomicAdd(&c_dd[d], 1); return; }
  i -= EDD + ND;
  if (i < EDT) { atomicAdd(&c_rv[dt_src[i]], 1); return; }
  i -= EDT;
  if (i < EDT) { atomicAdd(&c_dt[dt_dst[i]], 1); return; }
  i -= EDT;
  if (i < ETT + NT) { int d = (i < ETT) ? tt_dst[i] : i - ETT; atomicAdd(&c_tt[d], 1); }
}

__global__ __launch_bounds__(256) void scan6(
    const int* __restrict__ a0, int n0, int* __restrict__ o0,
    const int* __restrict__ a1, int n1, int* __restrict__ o1,
    const int* __restrict__ a2, int n2, int* __restrict__ o2,
    const int* __restrict__ a3, int n3, int* __restrict__ o3,
    const int* __restrict__ a4, int n4, int* __restrict__ o4,
    const int* __restrict__ a5, int n5, int* __restrict__ o5) {
  const int* a; int n; int* o;
  switch (blockIdx.x) {
    case 0: a = a0; n = n0; o = o0; break;
    case 1: a = a1; n = n1; o = o1; break;
    case 2: a = a2; n = n2; o = o2; break;
    case 3: a = a3; n = n3; o = o3; break;
    case 4: a = a4; n = n4; o = o4; break;
    default: a = a5; n = n5; o = o5; break;
  }
  __shared__ int part[256];
  int t = threadIdx.x;
  int strip = (n + 255) / 256;
  int lo = min(t * strip, n), hi = min(lo + strip, n);
  int s = 0;
  for (int i = lo; i < hi; ++i) s += a[i];
  part[t] = s;
  __syncthreads();
  if (t == 0) {
    int run = 0;
    for (int i = 0; i < 256; ++i) { int v = part[i]; part[i] = run; run += v; }
  }
  __syncthreads();
  int run = part[t];
  for (int i = lo; i < hi; ++i) { o[i] = run; run += a[i]; }
  if (hi == n) o[n] = run;
}

__global__ void ridx2(const int* __restrict__ mD, const int* __restrict__ cD,
                      int* __restrict__ rD,
                      const int* __restrict__ mT, const int* __restrict__ cT,
                      int* __restrict__ rT) {
  int i = blockIdx.x * 256 + threadIdx.x;
  if (i < ND) { if (mD[i] != 0) rD[cD[i]] = i; return; }
  i -= ND;
  if (i < NT) { if (mT[i] != 0) rT[cT[i]] = i; }
}

__global__ void fill4(const int* __restrict__ dd_src, const int* __restrict__ dd_dst,
                      const int* __restrict__ dt_src, const int* __restrict__ dt_dst,
                      const int* __restrict__ tt_src, const int* __restrict__ tt_dst,
                      const int* __restrict__ rp_dd, int* __restrict__ f_dd, int* __restrict__ ei_dd,
                      const int* __restrict__ rp_rv, int* __restrict__ f_rv, int* __restrict__ ei_rv,
                      const int* __restrict__ rp_dt, int* __restrict__ f_dt, int* __restrict__ ei_dt,
                      const int* __restrict__ rp_tt, int* __restrict__ f_tt, int* __restrict__ ei_tt) {
  int i = blockIdx.x * 256 + threadIdx.x;
  if (i < EDD + ND) {
    int s, d;
    if (i < EDD) { s = dd_src[i]; d = dd_dst[i]; } else { s = d = i - EDD; }
    ei_dd[rp_dd[d] + atomicAdd(&f_dd[d], 1)] = s;
    return;
  }
  i -= EDD + ND;
  if (i < EDT) {
    int d = dt_src[i], s = dt_dst[i];
    ei_rv[rp_rv[d] + atomicAdd(&f_rv[d], 1)] = s;
    return;
  }
  i -= EDT;
  if (i < EDT) {
    int d = dt_dst[i], s = dt_src[i];
    ei_dt[rp_dt[d] + atomicAdd(&f_dt[d], 1)] = s;
    return;
  }
  i -= EDT;
  if (i < ETT + NT) {
    int s, d;
    if (i < ETT) { s = tt_src[i]; d = tt_dst[i]; } else { s = d = i - ETT; }
    ei_tt[rp_tt[d] + atomicAdd(&f_tt[d], 1)] = s;
  }
}

// ---------------- fused dual-layer GAT aggregation, BOTH node types ----------------
__device__ __forceinline__ void fma4(float* acc, uint2 A, float al) {
  unsigned w;
  w = A.x; acc[0] += al * __uint_as_float(w << 16); acc[1] += al * __uint_as_float(w & 0xffff0000u);
  w = A.y; acc[2] += al * __uint_as_float(w << 16); acc[3] += al * __uint_as_float(w & 0xffff0000u);
}

__device__ __forceinline__ float lrexp(float v) {
  v = (v >= 0.f) ? v : 0.2f * v;
  return __expf(v);
}

__global__ __launch_bounds__(256) void gat_agg2(
    // common sources
    const unsigned short* __restrict__ A1, const unsigned short* __restrict__ A2,
    const int* __restrict__ msk1, const int* __restrict__ msk2,
    const void* __restrict__ tok1, const void* __restrict__ tok2,
    const float* __restrict__ tokscal,
    // drug-dst problem
    const int* __restrict__ rpD1, const int* __restrict__ eiD1,
    const float* __restrict__ esD1, const float* __restrict__ edD1,
    const int* __restrict__ rpD2, const int* __restrict__ eiD2,
    const float* __restrict__ esD2, const float* __restrict__ edD2,
    const int* __restrict__ cidxD,
    unsigned short* __restrict__ aggd1, unsigned short* __restrict__ aggd2,
    // target-dst problem
    const int* __restrict__ rpT1, const int* __restrict__ eiT1,
    const float* __restrict__ esT1, const float* __restrict__ edT1,
    const int* __restrict__ rpT2, const int* __restrict__ eiT2,
    const float* __restrict__ esT2, const float* __restrict__ edT2,
    const int* __restrict__ cidxT,
    unsigned short* __restrict__ aggt1, unsigned short* __restrict__ aggt2,
    const int* __restrict__ flag) {
  int gwid = (blockIdx.x * 256 + threadIdx.x) >> 6;
  int lane = threadIdx.x & 63;
  if (gwid >= ND + NT) return;
  int f32 = flag[0];

  const int *rp1, *ei1, *rp2, *ei2, *cidx;
  const float *es1, *ed1, *es2, *ed2, *ts;
  const int* mdst;
  unsigned short *agg1, *agg2;
  int wid;
  if (gwid < ND) {
    wid = gwid; mdst = msk1;
    rp1 = rpD1; ei1 = eiD1; es1 = esD1; ed1 = edD1;
    rp2 = rpD2; ei2 = eiD2; es2 = esD2; ed2 = edD2;
    cidx = cidxD; agg1 = aggd1; agg2 = aggd2; ts = tokscal;
  } else {
    wid = gwid - ND; mdst = msk2;
    rp1 = rpT1; ei1 = eiT1; es1 = esT1; ed1 = edT1;
    rp2 = rpT2; ei2 = eiT2; es2 = esT2; ed2 = edT2;
    cidx = cidxT; agg1 = aggt1; agg2 = aggt2; ts = tokscal + 4;
  }

  bool need2 = (mdst[wid] != 0);  // wave-uniform
  float ac1[13], ac2[13];
#pragma unroll
  for (int c = 0; c < 13; ++c) { ac1[c] = 0.f; ac2[c] = 0.f; }

  // ---------------- rel1: src rows from A1 [*, KPD] ----------------
  {
    float tes = ts[0], ted = ts[1];
    int lo = rp1[wid], hi = rp1[wid + 1];
    float edA = ed1[4 * (size_t)wid];
    float s1 = 0.f, s2 = 0.f;
    for (int e = lo + lane; e < hi; e += 64) {
      int sn = ei1[e];
      float ev = es1[4 * (size_t)sn];
      s1 += lrexp(ev + edA);
      if (need2) {
        float e2 = (msk1[sn] != 0) ? tes : ev;
        s2 += lrexp(e2 + ted);
      }
    }
    s1 = wave_reduce(s1);
    float i1 = 1.f / (s1 + 1e-16f), i2 = 0.f;
    if (need2) { s2 = wave_reduce(s2); i2 = 1.f / (s2 + 1e-16f); }
    float wt = 0.f;
    int pn = (lo < hi) ? ei1[lo] : 0;
    for (int e = lo; e < hi; ++e) {
      int sn = __builtin_amdgcn_readfirstlane(pn);
      if (e + 1 < hi) pn = ei1[e + 1];
      uint2 rv = *(const uint2*)(A1 + (size_t)sn * KPD + 4 * lane);
      float ev = es1[4 * (size_t)sn];
      fma4(ac1, rv, lrexp(ev + edA) * i1);
      if (need2) {
        if (msk1[sn] != 0) wt += lrexp(tes + ted) * i2;
        else fma4(ac2, rv, lrexp(ev + ted) * i2);
      }
    }
    if (need2) {
#pragma unroll
      for (int c = 0; c < 4; ++c) {
        int col = 4 * lane + c;
        float tv = (col < FD) ? ldx(tok1, col, f32) : 0.f;
        ac2[c] += wt * tv;
      }
    }
  }

  // ---------------- rel2: src rows from A2 [*, KPT] ----------------
  {
    float tes = ts[2], ted = ts[3];
    int lo = rp2[wid], hi = rp2[wid + 1];
    float edA = ed2[4 * (size_t)wid];
    float s1 = 0.f, s2 = 0.f;
    for (int e = lo + lane; e < hi; e += 64) {
      int sn = ei2[e];
      float ev = es2[4 * (size_t)sn];
      s1 += lrexp(ev + edA);
      if (need2) {
        float e2 = (msk2[sn] != 0) ? tes : ev;
        s2 += lrexp(e2 + ted);
      }
    }
    s1 = wave_reduce(s1);
    float i1 = 1.f / (s1 + 1e-16f), i2 = 0.f;
    if (need2) { s2 = wave_reduce(s2); i2 = 1.f / (s2 + 1e-16f); }
    float wt = 0.f;
    int pn = (lo < hi) ? ei2[lo] : 0;
    for (int e = lo; e < hi; ++e) {
      int sn = __builtin_amdgcn_readfirstlane(pn);
      if (e + 1 < hi) pn = ei2[e + 1];
      const unsigned short* row = A2 + (size_t)sn * KPT;
      uint2 ra = *(const uint2*)(row + 4 * lane);
      uint2 rb = *(const uint2*)(row + 256 + 4 * lane);
      unsigned short rc = row[512 + lane];
      float ev = es2[4 * (size_t)sn];
      float a1 = lrexp(ev + edA) * i1;
      fma4(ac1 + 4, ra, a1);
      fma4(ac1 + 8, rb, a1);
      ac1[12] += a1 * b2f(rc);
      if (need2) {
        if (msk2[sn] != 0) {
          wt += lrexp(tes + ted) * i2;
        } else {
          float a2 = lrexp(ev + ted) * i2;
          fma4(ac2 + 4, ra, a2);
          fma4(ac2 + 8, rb, a2);
          ac2[12] += a2 * b2f(rc);
        }
      }
    }
    if (need2) {
#pragma unroll
      for (int c = 0; c < 4; ++c) {
        int colA = 4 * lane + c;
        int colB = 256 + 4 * lane + c;
        ac2[4 + c] += wt * ldx(tok2, colA, f32);
        ac2[8 + c] += wt * ldx(tok2, colB, f32);
      }
      int colC = 512 + lane;
      ac2[12] += wt * ((colC < FT) ? ldx(tok2, colC, f32) : 0.f);
    }
  }

  // ---------------- store agg rows (bf16) ----------------
  unsigned short* o1 = agg1 + (size_t)wid * KPA;
  uint2 u;
  u.x = pk2(ac1[0], ac1[1]);  u.y = pk2(ac1[2], ac1[3]);  *(uint2*)(o1 + 4 * lane) = u;
  u.x = pk2(ac1[4], ac1[5]);  u.y = pk2(ac1[6], ac1[7]);  *(uint2*)(o1 + 256 + 4 * lane) = u;
  u.x = pk2(ac1[8], ac1[9]);  u.y = pk2(ac1[10], ac1[11]); *(uint2*)(o1 + 512 + 4 * lane) = u;
  o1[768 + lane] = f2b(ac1[12]);
  if (need2) {
    unsigned short* o2 = agg2 + (size_t)cidx[wid] * KPA;
    u.x = pk2(ac2[0], ac2[1]);  u.y = pk2(ac2[2], ac2[3]);  *(uint2*)(o2 + 4 * lane) = u;
    u.x = pk2(ac2[4], ac2[5]);  u.y = pk2(ac2[6], ac2[7]);  *(uint2*)(o2 + 256 + 4 * lane) = u;
    u.x = pk2(ac2[8], ac2[9]);  u.y = pk2(ac2[10], ac2[11]); *(uint2*)(o2 + 512 + 4 * lane) = u;
    o2[768 + lane] = f2b(ac2[12]);
  }
}

// ---------------- fused dual-problem MFMA GEMM ----------------
// GBK=32, 32KB LDS (A dbuf 2x8KB + B dbuf 2x8KB) -> 5 blocks/CU.
// 2-phase global_load_lds pipeline; XOR swizzle cs = (chunk&3)^((row>>1)&3)
// applied on BOTH stage-source and ds_read (rule #21).
// Epilogue: two half-passes through the 32KB LDS as 128x64 f32 (coalesced I/O).

__global__ __launch_bounds__(256) void gemm2(
    const unsigned short* __restrict__ A0, const unsigned short* __restrict__ B0,
    const void* __restrict__ c1_0, const void* __restrict__ c2_0,
    int M0s, const int* __restrict__ mc0, const int* __restrict__ rx0,
    unsigned long long base0, float* __restrict__ pp0,
    const unsigned short* __restrict__ A1, const unsigned short* __restrict__ B1,
    const void* __restrict__ c1_1, const void* __restrict__ c2_1,
    int M1s, const int* __restrict__ mc1, const int* __restrict__ rx1,
    unsigned long long base1, float* __restrict__ pp1,
    int mt0, int nwg, void* __restrict__ out, int mode,
    const int* __restrict__ flag) {
  __shared__ unsigned long long lds8[4096];  // 32KB
  unsigned short* ldsS = (unsigned short*)lds8;
  float* Cls = (float*)lds8;                 // epilogue: 128x64 f32

  // bijective XCD-chunk swizzle (m204)
  int b = blockIdx.x;
  int q = nwg >> 3, r = nwg & 7;
  int xcd = b & 7, pos = b >> 3;
  int wg = (xcd < r ? xcd * (q + 1) : r * (q + 1) + (xcd - r) * q) + pos;
  int prob = (wg >= 6 * mt0) ? 1 : 0;
  int rel = prob ? (wg - 6 * mt0) : wg;
  int mt = rel / 6, nt = rel - mt * 6;

  const unsigned short* A = prob ? A1 : A0;
  const unsigned short* Bt = prob ? B1 : B0;
  const void* c1 = prob ? c1_1 : c1_0;
  const void* c2 = prob ? c2_1 : c2_0;
  const int* mc = prob ? mc1 : mc0;
  const int* ridx = prob ? rx1 : rx0;
  size_t base = prob ? base1 : base0;
  float* parts = prob ? pp1 : pp0;
  int M = prob ? M1s : M0s;
  if (mc) M = *mc;
  int m0 = mt * BM;
  if (m0 >= M) return;
  int n0 = nt * BN;

  int t = threadIdx.x;
  int wave = t >> 6, lane = t & 63;
  int quad = lane >> 4, l15 = lane & 15;
  int wrow = (wave & 1) * 64, wcol = (wave >> 1) * 64;
  float4v acc[4][4];
#pragma unroll
  for (int i = 0; i < 4; ++i)
#pragma unroll
    for (int j = 0; j < 4; ++j) acc[i][j] = (float4v){0.f, 0.f, 0.f, 0.f};

  // stage one K-tile (128x32 each for A,B); 2 chunks per thread per matrix
  auto stage = [&](int buf, int k0) {
#pragma unroll
    for (int i = 0; i < 2; ++i) {
      int chunk = (wave * 2 + i) * 64 + lane;
      int row = chunk >> 2;
      int cs = (chunk & 3) ^ ((row >> 1) & 3);
      const unsigned short* ga = A + (size_t)(m0 + row) * KPA + k0 + cs * 8;
      __builtin_amdgcn_global_load_lds(
          (const __attribute__((address_space(1))) unsigned int*)ga,
          (__attribute__((address_space(3))) unsigned int*)(ldsS + buf * 4096 + (wave * 2 + i) * 512),
          16, 0, 0);
      const unsigned short* gb = Bt + (size_t)(n0 + row) * KPA + k0 + cs * 8;
      __builtin_amdgcn_global_load_lds(
          (const __attribute__((address_space(1))) unsigned int*)gb,
          (__attribute__((address_space(3))) unsigned int*)(ldsS + 8192 + buf * 4096 + (wave * 2 + i) * 512),
          16, 0, 0);
    }
  };
  auto compute = [&](int buf) {
    short8 a[4], bfr[4];
#pragma unroll
    for (int i = 0; i < 4; ++i) {
      int rr = wrow + i * 16 + l15;
      a[i] = *(const short8*)(ldsS + buf * 4096 + rr * 32 + ((quad ^ ((rr >> 1) & 3)) << 3));
    }
#pragma unroll
    for (int j = 0; j < 4; ++j) {
      int rc = wcol + j * 16 + l15;
      bfr[j] = *(const short8*)(ldsS + 8192 + buf * 4096 + rc * 32 + ((quad ^ ((rc >> 1) & 3)) << 3));
    }
#pragma unroll
    for (int i = 0; i < 4; ++i)
#pragma unroll
      for (int j = 0; j < 4; ++j)
        acc[i][j] = __builtin_amdgcn_mfma_f32_16x16x32_bf16(a[i], bfr[j], acc[i][j], 0, 0, 0);
  };

  stage(0, 0);
  __syncthreads();
  int cur = 0;
#pragma unroll 1
  for (int ks = 1; ks < KTILES; ++ks) {
    stage(cur ^ 1, ks * GBK);
    compute(cur);
    __syncthreads();
    cur ^= 1;
  }
  compute(cur);

  // ---------------- epilogue: two half-passes via 128x64 f32 LDS ----------------
  int f32 = flag[0];
  float bias[4];
#pragma unroll
  for (int j = 0; j < 4; ++j) {
    int n = n0 + wcol + j * 16 + l15;
    bias[j] = ldx(c1, n, f32) + ldx(c2, n, f32);
  }
  float cpart = 0.f;
#pragma unroll
  for (int h = 0; h < 2; ++h) {
    __syncthreads();   // staging (h=0) / prior half reads (h=1) complete
    if ((wave >> 1) == h) {  // this wave's cols live in half h
#pragma unroll
      for (int i = 0; i < 4; ++i)
#pragma unroll
        for (int j = 0; j < 4; ++j)
#pragma unroll
          for (int rr = 0; rr < 4; ++rr) {
            int row = wrow + i * 16 + quad * 4 + rr;
            int col = (j * 16 + l15) ^ (((row >> 2) & 1) << 4);  // bank rotate
            float v = acc[i][j][rr] + bias[j];
            Cls[row * 64 + col] = v > 0.f ? v : 0.f;
          }
    }
    __syncthreads();
#pragma unroll
    for (int i = 0; i < 8; ++i) {
      int ch = t + i * 256;           // 128 rows x 16 chunks of 4 cols
      int row = ch >> 4, cc = ch & 15;
      int m = m0 + row;
      if (m >= M) continue;
      int scc = cc ^ (((row >> 2) & 1) << 2);
      float4v v = *(const float4v*)(Cls + row * 64 + scc * 4);
      int n = n0 + h * 64 + cc * 4;
      if (mode == 1) {
        size_t idx = base + (size_t)m * HDIM + n;
        if (f32) {
          *(float4v*)((float*)out + idx) = v;
        } else {
          uint2 u; u.x = pk2(v[0], v[1]); u.y = pk2(v[2], v[3]);
          *(uint2*)((unsigned short*)out + idx) = u;
        }
      } else {
        int orig = ridx[m];
        size_t idx = base + (size_t)orig * HDIM + n;
        float d0, d1, d2, d3;
        if (f32) {
          float4v w = *(const float4v*)((const float*)out + idx);
          d0 = w[0] - v[0]; d1 = w[1] - v[1]; d2 = w[2] - v[2]; d3 = w[3] - v[3];
        } else {
          uint2 u = *(const uint2*)((const unsigned short*)out + idx);
          d0 = __uint_as_float(u.x << 16) - v[0];
          d1 = __uint_as_float(u.x & 0xffff0000u) - v[1];
          d2 = __uint_as_float(u.y << 16) - v[2];
          d3 = __uint_as_float(u.y & 0xffff0000u) - v[3];
        }
        cpart += d0 * d0 + d1 * d1 + d2 * d2 + d3 * d3;
      }
    }
  }
  if (mode == 2) {
    cpart = wave_reduce(cpart);
    if (lane == 0) atomicAdd(&parts[(wg * 4 + wave) & 2047], cpart);
  }
}

// ---------------- loss ----------------
__global__ __launch_bounds__(256) void loss_final(const float* __restrict__ parts,
                                                  const int* __restrict__ cd,
                                                  const int* __restrict__ ct,
                                                  void* __restrict__ out, size_t off,
                                                  const int* __restrict__ flag) {
  float a = 0.f, b = 0.f;
  for (int i = threadIdx.x; i < 2048; i += 256) { a += parts[i]; b += parts[2048 + i]; }
  a = wave_reduce(a);
  b = wave_reduce(b);
  __shared__ float ra[4], rb[4];
  if ((threadIdx.x & 63) == 0) { ra[threadIdx.x >> 6] = a; rb[threadIdx.x >> 6] = b; }
  __syncthreads();
  if (threadIdx.x == 0) {
    float sd = ra[0] + ra[1] + ra[2] + ra[3];
    float st = rb[0] + rb[1] + rb[2] + rb[3];
    float loss = sd / ((float)cd[0] * (float)HDIM + 1e-16f)
               + st / ((float)ct[0] * (float)HDIM + 1e-16f);
    stx(out, off, flag[0], loss);
  }
}

// ---------------- host ----------------

extern "C" void kernel_launch(void* const* d_in, const int* in_sizes, int n_in,
                              void* d_out, int out_size, void* d_ws, size_t ws_size,
                              hipStream_t stream) {
  const void* drug_x    = d_in[0];
  const void* target_x  = d_in[1];
  const int* dd_src = (const int*)d_in[2];
  const int* dd_dst = (const int*)d_in[3];
  const int* dt_src = (const int*)d_in[4];
  const int* dt_dst = (const int*)d_in[5];
  const int* tt_src = (const int*)d_in[6];
  const int* tt_dst = (const int*)d_in[7];
  const int* drug_mask   = (const int*)d_in[8];
  const int* target_mask = (const int*)d_in[9];
  const void* mask_drug   = d_in[10];
  const void* mask_target = d_in[11];
  const void* Wsrc_dd = d_in[12]; const void* Wdst_dd = d_in[13];
  const void* asrc_dd = d_in[14]; const void* adst_dd = d_in[15];
  const void* b_dd    = d_in[16];
  const void* Wsrc_dt = d_in[17]; const void* Wdst_dt = d_in[18];
  const void* asrc_dt = d_in[19]; const void* adst_dt = d_in[20];
  const void* b_dt    = d_in[21];
  const void* Wsrc_rv = d_in[22]; const void* Wdst_rv = d_in[23];
  const void* asrc_rv = d_in[24]; const void* adst_rv = d_in[25];
  const void* b_rv    = d_in[26];
  const void* Wsrc_tt = d_in[27]; const void* Wdst_tt = d_in[28];
  const void* asrc_tt = d_in[29]; const void* adst_tt = d_in[30];
  const void* b_tt    = d_in[31];

  char* p = (char*)d_ws;
  auto alloc = [&](size_t bytes) -> void* {
    void* r = (void*)p;
    p += (bytes + 255) & ~(size_t)255;
    return r;
  };
  const size_t PAD = (size_t)BM * KPA * 2;  // tile-overrun slack for gemm staging
  unsigned short* Ad    = (unsigned short*)alloc((size_t)ND * KPD * 2);
  unsigned short* At    = (unsigned short*)alloc((size_t)NT * KPT * 2);
  unsigned short* aggd1 = (unsigned short*)alloc((size_t)ND * KPA * 2 + PAD);
  unsigned short* aggd2 = (unsigned short*)alloc((size_t)ND * KPA * 2 + PAD);
  unsigned short* aggt1 = (unsigned short*)alloc((size_t)NT * KPA * 2 + PAD);
  unsigned short* aggt2 = (unsigned short*)alloc((size_t)NT * KPA * 2 + PAD);
  unsigned short* BdW   = (unsigned short*)alloc((size_t)HDIM * KPA * 2);
  unsigned short* BtW   = (unsigned short*)alloc((size_t)HDIM * KPA * 2);
  float* dvec1 = (float*)alloc((size_t)ND * 4 * 4);   // L1 {es_dd, ed_dd, ed_rv, es_dt}
  float* tvec1 = (float*)alloc((size_t)NT * 4 * 4);   // L1 {es_rv, ed_dt, es_tt, ed_tt}
  int* rp_dd = (int*)alloc((size_t)(ND + 1) * 4);
  int* rp_rv = (int*)alloc((size_t)(ND + 1) * 4);
  int* rp_dt = (int*)alloc((size_t)(NT + 1) * 4);
  int* rp_tt = (int*)alloc((size_t)(NT + 1) * 4);
  int* ei_dd = (int*)alloc((size_t)(EDD + ND) * 4);
  int* ei_rv = (int*)alloc((size_t)EDT * 4);
  int* ei_dt = (int*)alloc((size_t)EDT * 4);
  int* ei_tt = (int*)alloc((size_t)(ETT + NT) * 4);
  // zero-block: cnt4 | fill4 | parts (one zeroing launch)
  const int ZN = 4 * (ND + NT) + 4096;
  int* zblock = (int*)alloc((size_t)ZN * 4);
  int* cnt_dd = zblock;
  int* cnt_rv = cnt_dd + ND;
  int* cnt_dt = cnt_rv + ND;
  int* cnt_tt = cnt_dt + NT;
  int* f_dd   = cnt_tt + NT;
  int* f_rv   = f_dd + ND;
  int* f_dt   = f_rv + ND;
  int* f_tt   = f_dt + NT;
  float* parts = (float*)(f_tt + NT);
  int* cidxD = (int*)alloc((size_t)(ND + 1) * 4);
  int* cidxT = (int*)alloc((size_t)(NT + 1) * 4);
  int* ridxD = (int*)alloc((size_t)ND * 4);
  int* ridxT = (int*)alloc((size_t)NT * 4);
  float* vaD = (float*)alloc((size_t)4 * FD * 4);
  float* vaT = (float*)alloc((size_t)4 * FT * 4);
  float* tokscal = (float*)alloc(64);
  int*   flag  = (int*)alloc(256);

  // 1) dtype sniff + zero counters/fills/parts
  sniff<<<1, 256, 0, stream>>>(drug_x, flag);
  zero_i32<<<(ZN + 255) / 256, 256, 0, stream>>>(zblock, ZN);

  // 2) va vectors (one launch) + token dots
  {
    int waves = 4 * FD + 4 * FT;
    wa_dot8<<<(waves * 64 + 255) / 256, 256, 0, stream>>>(
        Wsrc_dd, Wdst_dd, Wdst_rv, Wsrc_dt, Wsrc_rv, Wdst_dt, Wsrc_tt, Wdst_tt,
        asrc_dd, adst_dd, adst_rv, asrc_dt, asrc_rv, adst_dt, asrc_tt, adst_tt,
        vaD, vaT, flag);
    tok_dots<<<1, 512, 0, stream>>>(mask_drug, mask_target, vaD, vaT, tokscal, flag);
  }

  // 3) pack both concat weights in one launch
  {
    long long tb = 2 * ((long long)HDIM * KPA / 4);
    pack_bTa2<<<(int)((tb + 255) / 256), 256, 0, stream>>>(Wsrc_dd, Wsrc_rv, BdW,
                                                           Wsrc_dt, Wsrc_tt, BtW, flag);
  }

  // 4) CSR build + mask compaction (batched)
  {
    int total = (EDD + ND) + EDT + EDT + (ETT + NT);
    count4<<<(total + 255) / 256, 256, 0, stream>>>(dd_dst, dt_src, dt_dst, tt_dst,
                                                    cnt_dd, cnt_rv, cnt_dt, cnt_tt);
    scan6<<<6, 256, 0, stream>>>(cnt_dd, ND, rp_dd, cnt_rv, ND, rp_rv,
                                 cnt_dt, NT, rp_dt, cnt_tt, NT, rp_tt,
                                 drug_mask, ND, cidxD, target_mask, NT, cidxT);
    ridx2<<<(ND + NT + 255) / 256, 256, 0, stream>>>(drug_mask, cidxD, ridxD,
                                                     target_mask, cidxT, ridxT);
    fill4<<<(total + 255) / 256, 256, 0, stream>>>(dd_src, dd_dst, dt_src, dt_dst,
                                                   tt_src, tt_dst,
                                                   rp_dd, f_dd, ei_dd, rp_rv, f_rv, ei_rv,
                                                   rp_dt, f_dt, ei_dt, rp_tt, f_tt, ei_tt);
  }

  // 5) fused pack + es/ed dots (x read once, both node types)
  pack_rowdot<<<((ND + NT) * 64 + 255) / 256, 256, 0, stream>>>(
      drug_x, target_x, vaD, vaT, Ad, At, dvec1, tvec1, flag);

  // 6) merged dual-layer gather (both dst node types in one launch)
  gat_agg2<<<(ND + NT + 3) / 4, 256, 0, stream>>>(
      Ad, At, drug_mask, target_mask, mask_drug, mask_target, tokscal,
      rp_dd, ei_dd, dvec1 + 0, dvec1 + 1,
      rp_rv, ei_rv, tvec1 + 0, dvec1 + 2,
      cidxD, aggd1, aggd2,
      rp_dt, ei_dt, dvec1 + 3, tvec1 + 1,
      rp_tt, ei_tt, tvec1 + 2, tvec1 + 3,
      cidxT, aggt1, aggt2, flag);

  size_t baseT = (size_t)ND * HDIM;
  size_t baseL = baseT + (size_t)NT * HDIM;

  // 7) fused output GEMMs (layer1 stores; layer2 compact rows -> fused loss)
  const int NWG = 6 * (MTD + MTT);
  gemm2<<<NWG, 256, 0, stream>>>(
      aggd1, BdW, b_dd, b_rv, ND, nullptr, nullptr, 0ULL, parts,
      aggt1, BtW, b_dt, b_tt, NT, nullptr, nullptr, (unsigned long long)baseT, parts,
      MTD, NWG, d_out, 1, flag);
  gemm2<<<NWG, 256, 0, stream>>>(
      aggd2, BdW, b_dd, b_rv, ND, cidxD + ND, ridxD, 0ULL, parts,
      aggt2, BtW, b_dt, b_tt, NT, cidxT + NT, ridxT, (unsigned long long)baseT, parts + 2048,
      MTD, NWG, d_out, 2, flag);

  loss_final<<<1, 256, 0, stream>>>(parts, cidxD + ND, cidxT + NT, d_out, baseL, flag);
}

// Round 7
// 918.100 us; speedup vs baseline: 1.0297x; 1.0297x over previous
//
#include <hip/hip_runtime.h>
#include <hip/hip_bf16.h>

#define ND 30000
#define NT 15000
#define FD 200
#define FT 570
#define HDIM 768
#define EDD 300000
#define EDT 400000
#define ETT 200000

#define KPD 256   // FD padded to x64 (gather rel1 row: 512B)
#define KPT 576   // FT padded to x64 (gather rel2 row: 1152B)
#define KPA 832   // agg K = KPD + KPT (concat), GEMM K dim

#define BM 128
#define BN 128
#define GBK 32
#define KTILES (KPA / GBK)         // 26
#define MTD ((ND + BM - 1) / BM)   // 235
#define MTT ((NT + BM - 1) / BM)   // 118

typedef __attribute__((ext_vector_type(8))) short short8;
typedef __attribute__((ext_vector_type(4))) float float4v;

// ---------------- dtype-adaptive load/store ----------------
// flag[0]: 0 = harness float tensors are bf16, 1 = fp32.

__device__ __forceinline__ float ldx(const void* p, size_t i, int f32) {
  return f32 ? ((const float*)p)[i]
             : __bfloat162float(((const __hip_bfloat16*)p)[i]);
}
__device__ __forceinline__ void stx(void* p, size_t i, int f32, float v) {
  if (f32) ((float*)p)[i] = v;
  else     ((__hip_bfloat16*)p)[i] = __float2bfloat16(v);
}
__device__ __forceinline__ float b2f(unsigned short u) {
  return __uint_as_float(((unsigned)u) << 16);
}
__device__ __forceinline__ unsigned short f2b(float f) {
  __hip_bfloat16 h = __float2bfloat16(f);
  return *(unsigned short*)&h;
}
__device__ __forceinline__ unsigned pk2(float a, float b) {
  return (unsigned)f2b(a) | ((unsigned)f2b(b) << 16);
}

__device__ __forceinline__ float wave_reduce(float v) {
#pragma unroll
  for (int off = 32; off > 0; off >>= 1) v += __shfl_xor(v, off, 64);
  return v;
}

// ---------------- dtype sniffer ----------------
__global__ void sniff(const void* x, int* flag) {
  int t = threadIdx.x;
  float cnt = 0.f;
  for (int i = t; i < 8192; i += 256) {
    float v = __bfloat162float(((const __hip_bfloat16*)x)[i]);
    if (!(fabsf(v) < 100.f)) cnt += 1.f;  // true for NaN too
  }
  cnt = wave_reduce(cnt);
  __shared__ float red[4];
  if ((t & 63) == 0) red[t >> 6] = cnt;
  __syncthreads();
  if (t == 0) flag[0] = (red[0] + red[1] + red[2] + red[3] > 256.f) ? 1 : 0;
}

// -------- all 8 va vectors in one launch: va[k] = sum_h W[k,h]*a[h] --------
__global__ __launch_bounds__(256) void wa_dot8(
    const void* W0, const void* W1, const void* W2, const void* W3,
    const void* W4, const void* W5, const void* W6, const void* W7,
    const void* a0, const void* a1, const void* a2, const void* a3,
    const void* a4, const void* a5, const void* a6, const void* a7,
    float* __restrict__ vaD, float* __restrict__ vaT,
    const int* __restrict__ flag) {
  const void* Ws[8] = {W0, W1, W2, W3, W4, W5, W6, W7};
  const void* as[8] = {a0, a1, a2, a3, a4, a5, a6, a7};
  int f32 = flag[0];
  int wid = (blockIdx.x * 256 + threadIdx.x) >> 6;
  int lane = threadIdx.x & 63;
  const void* W; const void* a; float* out; int k;
  if (wid < 4 * FD) {
    int q = wid / FD; k = wid - q * FD;
    W = Ws[q]; a = as[q]; out = vaD + q * FD + k;
  } else {
    int w2 = wid - 4 * FD;
    if (w2 >= 4 * FT) return;
    int q = w2 / FT; k = w2 - q * FT;
    W = Ws[4 + q]; a = as[4 + q]; out = vaT + q * FT + k;
  }
  float acc = 0.f;
  for (int h = lane; h < HDIM; h += 64)
    acc += ldx(W, (size_t)k * HDIM + h, f32) * ldx(a, h, f32);
  acc = wave_reduce(acc);
  if (lane == 0) *out = acc;
}

// -------- token-dot scalars: ts layout {D0,D1,T0,D2, D3,T1,T2,T3} --------
__global__ void tok_dots(const void* __restrict__ tok1, const void* __restrict__ tok2,
                         const float* __restrict__ vaD, const float* __restrict__ vaT,
                         float* __restrict__ ts, const int* __restrict__ flag) {
  int w = threadIdx.x >> 6;   // 0..7 (512 threads)
  int lane = threadIdx.x & 63;
  int f32 = flag[0];
  float acc = 0.f;
  if (w < 4) {
    for (int k = lane; k < FD; k += 64) acc += ldx(tok1, k, f32) * vaD[w * FD + k];
  } else {
    int q = w - 4;
    for (int k = lane; k < FT; k += 64) acc += ldx(tok2, k, f32) * vaT[q * FT + k];
  }
  acc = wave_reduce(acc);
  if (lane == 0) {
    const int map[8] = {0, 1, 3, 4, 2, 5, 6, 7};  // w -> ts slot
    ts[map[w]] = acc;
  }
}

// ------ fused pack (x -> bf16 padded) + 4 row dots, both node types ------
__global__ __launch_bounds__(256) void pack_rowdot(
    const void* __restrict__ xD, const void* __restrict__ xT,
    const float* __restrict__ vaD, const float* __restrict__ vaT,
    unsigned short* __restrict__ Ad, unsigned short* __restrict__ At,
    float* __restrict__ dvec, float* __restrict__ tvec,
    const int* __restrict__ flag) {
  int wid = (blockIdx.x * 256 + threadIdx.x) >> 6;
  int lane = threadIdx.x & 63;
  int f32 = flag[0];
  const void* x; const float* va; unsigned short* Aout; float* outv; int K, Kp, row;
  if (wid < ND) { x = xD; va = vaD; Aout = Ad; outv = dvec; K = FD; Kp = KPD; row = wid; }
  else if (wid < ND + NT) { x = xT; va = vaT; Aout = At; outv = tvec; K = FT; Kp = KPT; row = wid - ND; }
  else return;
  float a0 = 0.f, a1 = 0.f, a2 = 0.f, a3 = 0.f;
  for (int it = 0; it * 256 < Kp; ++it) {
    int base = 4 * lane + it * 256;
    if (base >= Kp) continue;
    ushort4 o;
    unsigned short r[4];
    float fv[4];
#pragma unroll
    for (int c = 0; c < 4; ++c) {
      int kk = base + c;
      float f = (kk < K) ? ldx(x, (size_t)row * K + kk, f32) : 0.f;
      fv[c] = f;
      r[c] = f2b(f);
    }
    o.x = r[0]; o.y = r[1]; o.z = r[2]; o.w = r[3];
    *(ushort4*)(Aout + (size_t)row * Kp + base) = o;
#pragma unroll
    for (int c = 0; c < 4; ++c) {
      int kk = base + c;
      if (kk < K) {
        a0 += fv[c] * va[kk];
        a1 += fv[c] * va[K + kk];
        a2 += fv[c] * va[2 * K + kk];
        a3 += fv[c] * va[3 * K + kk];
      }
    }
  }
  a0 = wave_reduce(a0); a1 = wave_reduce(a1);
  a2 = wave_reduce(a2); a3 = wave_reduce(a3);
  if (lane == 0) {
    float* o = outv + (size_t)row * 4;
    o[0] = a0; o[1] = a1; o[2] = a2; o[3] = a3;
  }
}

// ------ pack both concat B^T [768][832] in one launch ------
__global__ __launch_bounds__(256) void pack_bTa2(
    const void* __restrict__ W1a, const void* __restrict__ W2a, unsigned short* __restrict__ Ba,
    const void* __restrict__ W1b, const void* __restrict__ W2b, unsigned short* __restrict__ Bb,
    const int* __restrict__ flag) {
  int f32 = flag[0];
  long long one = (long long)HDIM * KPA / 4;
  long long gid = (long long)blockIdx.x * 256 + threadIdx.x;
  if (gid >= 2 * one) return;
  const void* W1; const void* W2; unsigned short* Bout;
  if (gid < one) { W1 = W1a; W2 = W2a; Bout = Ba; }
  else { W1 = W1b; W2 = W2b; Bout = Bb; gid -= one; }
  long long e0 = gid * 4;
  int n = (int)(e0 / KPA);
  int k = (int)(e0 % KPA);
  ushort4 o;
  unsigned short r[4];
#pragma unroll
  for (int c = 0; c < 4; ++c) {
    int kk = k + c;
    float f = 0.f;
    if (kk < 256) {
      if (kk < FD) f = ldx(W1, (size_t)kk * HDIM + n, f32);
    } else {
      int k2 = kk - 256;
      if (k2 < FT) f = ldx(W2, (size_t)k2 * HDIM + n, f32);
    }
    r[c] = f2b(f);
  }
  o.x = r[0]; o.y = r[1]; o.z = r[2]; o.w = r[3];
  *(ushort4*)(Bout + e0) = o;
}

// ---------------- batched graph-prep kernels ----------------
__global__ void zero_i32(int* __restrict__ p, int n) {
  int i = blockIdx.x * 256 + threadIdx.x;
  if (i < n) p[i] = 0;
}

__global__ void count4(const int* __restrict__ dd_dst, const int* __restrict__ dt_src,
                       const int* __restrict__ dt_dst, const int* __restrict__ tt_dst,
                       int* __restrict__ c_dd, int* __restrict__ c_rv,
                       int* __restrict__ c_dt, int* __restrict__ c_tt) {
  int i = blockIdx.x * 256 + threadIdx.x;
  if (i < EDD + ND) { int d = (i < EDD) ? dd_dst[i] : i - EDD; atomicAdd(&c_dd[d], 1); return; }
  i -= EDD + ND;
  if (i < EDT) { atomicAdd(&c_rv[dt_src[i]], 1); return; }
  i -= EDT;
  if (i < EDT) { atomicAdd(&c_dt[dt_dst[i]], 1); return; }
  i -= EDT;
  if (i < ETT + NT) { int d = (i < ETT) ? tt_dst[i] : i - ETT; atomicAdd(&c_tt[d], 1); }
}

__global__ __launch_bounds__(256) void scan6(
    const int* __restrict__ a0, int n0, int* __restrict__ o0,
    const int* __restrict__ a1, int n1, int* __restrict__ o1,
    const int* __restrict__ a2, int n2, int* __restrict__ o2,
    const int* __restrict__ a3, int n3, int* __restrict__ o3,
    const int* __restrict__ a4, int n4, int* __restrict__ o4,
    const int* __restrict__ a5, int n5, int* __restrict__ o5) {
  const int* a; int n; int* o;
  switch (blockIdx.x) {
    case 0: a = a0; n = n0; o = o0; break;
    case 1: a = a1; n = n1; o = o1; break;
    case 2: a = a2; n = n2; o = o2; break;
    case 3: a = a3; n = n3; o = o3; break;
    case 4: a = a4; n = n4; o = o4; break;
    default: a = a5; n = n5; o = o5; break;
  }
  __shared__ int part[256];
  int t = threadIdx.x;
  int strip = (n + 255) / 256;
  int lo = min(t * strip, n), hi = min(lo + strip, n);
  int s = 0;
  for (int i = lo; i < hi; ++i) s += a[i];
  part[t] = s;
  __syncthreads();
  if (t == 0) {
    int run = 0;
    for (int i = 0; i < 256; ++i) { int v = part[i]; part[i] = run; run += v; }
  }
  __syncthreads();
  int run = part[t];
  for (int i = lo; i < hi; ++i) { o[i] = run; run += a[i]; }
  if (hi == n) o[n] = run;
}

__global__ void ridx2(const int* __restrict__ mD, const int* __restrict__ cD,
                      int* __restrict__ rD,
                      const int* __restrict__ mT, const int* __restrict__ cT,
                      int* __restrict__ rT) {
  int i = blockIdx.x * 256 + threadIdx.x;
  if (i < ND) { if (mD[i] != 0) rD[cD[i]] = i; return; }
  i -= ND;
  if (i < NT) { if (mT[i] != 0) rT[cT[i]] = i; }
}

__global__ void fill4(const int* __restrict__ dd_src, const int* __restrict__ dd_dst,
                      const int* __restrict__ dt_src, const int* __restrict__ dt_dst,
                      const int* __restrict__ tt_src, const int* __restrict__ tt_dst,
                      const int* __restrict__ rp_dd, int* __restrict__ f_dd, int* __restrict__ ei_dd,
                      const int* __restrict__ rp_rv, int* __restrict__ f_rv, int* __restrict__ ei_rv,
                      const int* __restrict__ rp_dt, int* __restrict__ f_dt, int* __restrict__ ei_dt,
                      const int* __restrict__ rp_tt, int* __restrict__ f_tt, int* __restrict__ ei_tt) {
  int i = blockIdx.x * 256 + threadIdx.x;
  if (i < EDD + ND) {
    int s, d;
    if (i < EDD) { s = dd_src[i]; d = dd_dst[i]; } else { s = d = i - EDD; }
    ei_dd[rp_dd[d] + atomicAdd(&f_dd[d], 1)] = s;
    return;
  }
  i -= EDD + ND;
  if (i < EDT) {
    int d = dt_src[i], s = dt_dst[i];
    ei_rv[rp_rv[d] + atomicAdd(&f_rv[d], 1)] = s;
    return;
  }
  i -= EDT;
  if (i < EDT) {
    int d = dt_dst[i], s = dt_src[i];
    ei_dt[rp_dt[d] + atomicAdd(&f_dt[d], 1)] = s;
    return;
  }
  i -= EDT;
  if (i < ETT + NT) {
    int s, d;
    if (i < ETT) { s = tt_src[i]; d = tt_dst[i]; } else { s = d = i - ETT; }
    ei_tt[rp_tt[d] + atomicAdd(&f_tt[d], 1)] = s;
  }
}

// ---------------- fused dual-layer GAT aggregation, BOTH node types ----------------
__device__ __forceinline__ void fma4(float* acc, uint2 A, float al) {
  unsigned w;
  w = A.x; acc[0] += al * __uint_as_float(w << 16); acc[1] += al * __uint_as_float(w & 0xffff0000u);
  w = A.y; acc[2] += al * __uint_as_float(w << 16); acc[3] += al * __uint_as_float(w & 0xffff0000u);
}

__device__ __forceinline__ float lrexp(float v) {
  v = (v >= 0.f) ? v : 0.2f * v;
  return __expf(v);
}

__global__ __launch_bounds__(256) void gat_agg2(
    // common sources
    const unsigned short* __restrict__ A1, const unsigned short* __restrict__ A2,
    const int* __restrict__ msk1, const int* __restrict__ msk2,
    const void* __restrict__ tok1, const void* __restrict__ tok2,
    const float* __restrict__ tokscal,
    // drug-dst problem
    const int* __restrict__ rpD1, const int* __restrict__ eiD1,
    const float* __restrict__ esD1, const float* __restrict__ edD1,
    const int* __restrict__ rpD2, const int* __restrict__ eiD2,
    const float* __restrict__ esD2, const float* __restrict__ edD2,
    const int* __restrict__ cidxD,
    unsigned short* __restrict__ aggd1, unsigned short* __restrict__ aggd2,
    // target-dst problem
    const int* __restrict__ rpT1, const int* __restrict__ eiT1,
    const float* __restrict__ esT1, const float* __restrict__ edT1,
    const int* __restrict__ rpT2, const int* __restrict__ eiT2,
    const float* __restrict__ esT2, const float* __restrict__ edT2,
    const int* __restrict__ cidxT,
    unsigned short* __restrict__ aggt1, unsigned short* __restrict__ aggt2,
    const int* __restrict__ flag) {
  int gwid = (blockIdx.x * 256 + threadIdx.x) >> 6;
  int lane = threadIdx.x & 63;
  if (gwid >= ND + NT) return;
  int f32 = flag[0];

  const int *rp1, *ei1, *rp2, *ei2, *cidx;
  const float *es1, *ed1, *es2, *ed2, *ts;
  const int* mdst;
  unsigned short *agg1, *agg2;
  int wid;
  if (gwid < ND) {
    wid = gwid; mdst = msk1;
    rp1 = rpD1; ei1 = eiD1; es1 = esD1; ed1 = edD1;
    rp2 = rpD2; ei2 = eiD2; es2 = esD2; ed2 = edD2;
    cidx = cidxD; agg1 = aggd1; agg2 = aggd2; ts = tokscal;
  } else {
    wid = gwid - ND; mdst = msk2;
    rp1 = rpT1; ei1 = eiT1; es1 = esT1; ed1 = edT1;
    rp2 = rpT2; ei2 = eiT2; es2 = esT2; ed2 = edT2;
    cidx = cidxT; agg1 = aggt1; agg2 = aggt2; ts = tokscal + 4;
  }

  bool need2 = (mdst[wid] != 0);  // wave-uniform
  float ac1[13], ac2[13];
#pragma unroll
  for (int c = 0; c < 13; ++c) { ac1[c] = 0.f; ac2[c] = 0.f; }

  // ---------------- rel1: src rows from A1 [*, KPD] ----------------
  {
    float tes = ts[0], ted = ts[1];
    int lo = rp1[wid], hi = rp1[wid + 1];
    float edA = ed1[4 * (size_t)wid];
    float s1 = 0.f, s2 = 0.f;
    for (int e = lo + lane; e < hi; e += 64) {
      int sn = ei1[e];
      float ev = es1[4 * (size_t)sn];
      s1 += lrexp(ev + edA);
      if (need2) {
        float e2 = (msk1[sn] != 0) ? tes : ev;
        s2 += lrexp(e2 + ted);
      }
    }
    s1 = wave_reduce(s1);
    float i1 = 1.f / (s1 + 1e-16f), i2 = 0.f;
    if (need2) { s2 = wave_reduce(s2); i2 = 1.f / (s2 + 1e-16f); }
    float wt = 0.f;
    int pn = (lo < hi) ? ei1[lo] : 0;
    for (int e = lo; e < hi; ++e) {
      int sn = __builtin_amdgcn_readfirstlane(pn);
      if (e + 1 < hi) pn = ei1[e + 1];
      uint2 rv = *(const uint2*)(A1 + (size_t)sn * KPD + 4 * lane);
      float ev = es1[4 * (size_t)sn];
      fma4(ac1, rv, lrexp(ev + edA) * i1);
      if (need2) {
        if (msk1[sn] != 0) wt += lrexp(tes + ted) * i2;
        else fma4(ac2, rv, lrexp(ev + ted) * i2);
      }
    }
    if (need2) {
#pragma unroll
      for (int c = 0; c < 4; ++c) {
        int col = 4 * lane + c;
        float tv = (col < FD) ? ldx(tok1, col, f32) : 0.f;
        ac2[c] += wt * tv;
      }
    }
  }

  // ---------------- rel2: src rows from A2 [*, KPT] ----------------
  {
    float tes = ts[2], ted = ts[3];
    int lo = rp2[wid], hi = rp2[wid + 1];
    float edA = ed2[4 * (size_t)wid];
    float s1 = 0.f, s2 = 0.f;
    for (int e = lo + lane; e < hi; e += 64) {
      int sn = ei2[e];
      float ev = es2[4 * (size_t)sn];
      s1 += lrexp(ev + edA);
      if (need2) {
        float e2 = (msk2[sn] != 0) ? tes : ev;
        s2 += lrexp(e2 + ted);
      }
    }
    s1 = wave_reduce(s1);
    float i1 = 1.f / (s1 + 1e-16f), i2 = 0.f;
    if (need2) { s2 = wave_reduce(s2); i2 = 1.f / (s2 + 1e-16f); }
    float wt = 0.f;
    int pn = (lo < hi) ? ei2[lo] : 0;
    for (int e = lo; e < hi; ++e) {
      int sn = __builtin_amdgcn_readfirstlane(pn);
      if (e + 1 < hi) pn = ei2[e + 1];
      const unsigned short* row = A2 + (size_t)sn * KPT;
      uint2 ra = *(const uint2*)(row + 4 * lane);
      uint2 rb = *(const uint2*)(row + 256 + 4 * lane);
      unsigned short rc = row[512 + lane];
      float ev = es2[4 * (size_t)sn];
      float a1 = lrexp(ev + edA) * i1;
      fma4(ac1 + 4, ra, a1);
      fma4(ac1 + 8, rb, a1);
      ac1[12] += a1 * b2f(rc);
      if (need2) {
        if (msk2[sn] != 0) {
          wt += lrexp(tes + ted) * i2;
        } else {
          float a2 = lrexp(ev + ted) * i2;
          fma4(ac2 + 4, ra, a2);
          fma4(ac2 + 8, rb, a2);
          ac2[12] += a2 * b2f(rc);
        }
      }
    }
    if (need2) {
#pragma unroll
      for (int c = 0; c < 4; ++c) {
        int colA = 4 * lane + c;
        int colB = 256 + 4 * lane + c;
        ac2[4 + c] += wt * ldx(tok2, colA, f32);
        ac2[8 + c] += wt * ldx(tok2, colB, f32);
      }
      int colC = 512 + lane;
      ac2[12] += wt * ((colC < FT) ? ldx(tok2, colC, f32) : 0.f);
    }
  }

  // ---------------- store agg rows (bf16) ----------------
  unsigned short* o1 = agg1 + (size_t)wid * KPA;
  uint2 u;
  u.x = pk2(ac1[0], ac1[1]);  u.y = pk2(ac1[2], ac1[3]);  *(uint2*)(o1 + 4 * lane) = u;
  u.x = pk2(ac1[4], ac1[5]);  u.y = pk2(ac1[6], ac1[7]);  *(uint2*)(o1 + 256 + 4 * lane) = u;
  u.x = pk2(ac1[8], ac1[9]);  u.y = pk2(ac1[10], ac1[11]); *(uint2*)(o1 + 512 + 4 * lane) = u;
  o1[768 + lane] = f2b(ac1[12]);
  if (need2) {
    unsigned short* o2 = agg2 + (size_t)cidx[wid] * KPA;
    u.x = pk2(ac2[0], ac2[1]);  u.y = pk2(ac2[2], ac2[3]);  *(uint2*)(o2 + 4 * lane) = u;
    u.x = pk2(ac2[4], ac2[5]);  u.y = pk2(ac2[6], ac2[7]);  *(uint2*)(o2 + 256 + 4 * lane) = u;
    u.x = pk2(ac2[8], ac2[9]);  u.y = pk2(ac2[10], ac2[11]); *(uint2*)(o2 + 512 + 4 * lane) = u;
    o2[768 + lane] = f2b(ac2[12]);
  }
}

// ---------------- fused dual-problem MFMA GEMM ----------------
// GBK=32, 32KB LDS dbuf -> 5 blocks/CU. Counted-vmcnt pipeline (T4):
// stage(next) -> s_waitcnt vmcnt(4) (cur landed, next stays in flight) ->
// s_barrier -> compute(cur) -> s_barrier (cur safe to restage).
// XOR swizzle cs = (chunk&3)^((row>>1)&3) on BOTH stage-source and ds_read.
// Epilogue: two half-passes through the 32KB LDS as 128x64 f32 (coalesced I/O).

__global__ __launch_bounds__(256) void gemm2(
    const unsigned short* __restrict__ A0, const unsigned short* __restrict__ B0,
    const void* __restrict__ c1_0, const void* __restrict__ c2_0,
    int M0s, const int* __restrict__ mc0, const int* __restrict__ rx0,
    unsigned long long base0, float* __restrict__ pp0,
    const unsigned short* __restrict__ A1, const unsigned short* __restrict__ B1,
    const void* __restrict__ c1_1, const void* __restrict__ c2_1,
    int M1s, const int* __restrict__ mc1, const int* __restrict__ rx1,
    unsigned long long base1, float* __restrict__ pp1,
    int mt0, int nwg, void* __restrict__ out, int mode,
    const int* __restrict__ flag) {
  __shared__ unsigned long long lds8[4096];  // 32KB
  unsigned short* ldsS = (unsigned short*)lds8;
  float* Cls = (float*)lds8;                 // epilogue: 128x64 f32

  // bijective XCD-chunk swizzle (m204)
  int b = blockIdx.x;
  int q = nwg >> 3, r = nwg & 7;
  int xcd = b & 7, pos = b >> 3;
  int wg = (xcd < r ? xcd * (q + 1) : r * (q + 1) + (xcd - r) * q) + pos;
  int prob = (wg >= 6 * mt0) ? 1 : 0;
  int rel = prob ? (wg - 6 * mt0) : wg;
  int mt = rel / 6, nt = rel - mt * 6;

  const unsigned short* A = prob ? A1 : A0;
  const unsigned short* Bt = prob ? B1 : B0;
  const void* c1 = prob ? c1_1 : c1_0;
  const void* c2 = prob ? c2_1 : c2_0;
  const int* mc = prob ? mc1 : mc0;
  const int* ridx = prob ? rx1 : rx0;
  size_t base = prob ? base1 : base0;
  float* parts = prob ? pp1 : pp0;
  int M = prob ? M1s : M0s;
  if (mc) M = *mc;
  int m0 = mt * BM;
  if (m0 >= M) return;
  int n0 = nt * BN;

  int t = threadIdx.x;
  int wave = t >> 6, lane = t & 63;
  int quad = lane >> 4, l15 = lane & 15;
  int wrow = (wave & 1) * 64, wcol = (wave >> 1) * 64;
  float4v acc[4][4];
#pragma unroll
  for (int i = 0; i < 4; ++i)
#pragma unroll
    for (int j = 0; j < 4; ++j) acc[i][j] = (float4v){0.f, 0.f, 0.f, 0.f};

  // stage one K-tile (128x32 each for A,B); 4 gload_lds per wave per stage
  auto stage = [&](int buf, int k0) {
#pragma unroll
    for (int i = 0; i < 2; ++i) {
      int chunk = (wave * 2 + i) * 64 + lane;
      int row = chunk >> 2;
      int cs = (chunk & 3) ^ ((row >> 1) & 3);
      const unsigned short* ga = A + (size_t)(m0 + row) * KPA + k0 + cs * 8;
      __builtin_amdgcn_global_load_lds(
          (const __attribute__((address_space(1))) unsigned int*)ga,
          (__attribute__((address_space(3))) unsigned int*)(ldsS + buf * 4096 + (wave * 2 + i) * 512),
          16, 0, 0);
      const unsigned short* gb = Bt + (size_t)(n0 + row) * KPA + k0 + cs * 8;
      __builtin_amdgcn_global_load_lds(
          (const __attribute__((address_space(1))) unsigned int*)gb,
          (__attribute__((address_space(3))) unsigned int*)(ldsS + 8192 + buf * 4096 + (wave * 2 + i) * 512),
          16, 0, 0);
    }
  };
  auto compute = [&](int buf) {
    short8 a[4], bfr[4];
#pragma unroll
    for (int i = 0; i < 4; ++i) {
      int rr = wrow + i * 16 + l15;
      a[i] = *(const short8*)(ldsS + buf * 4096 + rr * 32 + ((quad ^ ((rr >> 1) & 3)) << 3));
    }
#pragma unroll
    for (int j = 0; j < 4; ++j) {
      int rc = wcol + j * 16 + l15;
      bfr[j] = *(const short8*)(ldsS + 8192 + buf * 4096 + rc * 32 + ((quad ^ ((rc >> 1) & 3)) << 3));
    }
#pragma unroll
    for (int i = 0; i < 4; ++i)
#pragma unroll
      for (int j = 0; j < 4; ++j)
        acc[i][j] = __builtin_amdgcn_mfma_f32_16x16x32_bf16(a[i], bfr[j], acc[i][j], 0, 0, 0);
  };

  // ---- counted-vmcnt 2-phase pipeline ----
  stage(0, 0);                       // 4 loads in flight
  int cur = 0;
#pragma unroll 1
  for (int ks = 1; ks < KTILES; ++ks) {
    stage(cur ^ 1, ks * GBK);        // +4 -> 8 in flight
    asm volatile("s_waitcnt vmcnt(4)" ::: "memory");  // cur's 4 landed; next stays in flight
    __builtin_amdgcn_sched_barrier(0);
    __builtin_amdgcn_s_barrier();    // cur visible to all waves
    compute(cur);
    __builtin_amdgcn_s_barrier();    // all waves done reading cur before restage
    cur ^= 1;
  }
  asm volatile("s_waitcnt vmcnt(0)" ::: "memory");
  __builtin_amdgcn_sched_barrier(0);
  __builtin_amdgcn_s_barrier();
  compute(cur);

  // ---------------- epilogue: two half-passes via 128x64 f32 LDS ----------------
  int f32 = flag[0];
  float bias[4];
#pragma unroll
  for (int j = 0; j < 4; ++j) {
    int n = n0 + wcol + j * 16 + l15;
    bias[j] = ldx(c1, n, f32) + ldx(c2, n, f32);
  }
  float cpart = 0.f;
#pragma unroll
  for (int h = 0; h < 2; ++h) {
    __syncthreads();   // staging (h=0) / prior half reads (h=1) complete
    if ((wave >> 1) == h) {  // this wave's cols live in half h
#pragma unroll
      for (int i = 0; i < 4; ++i)
#pragma unroll
        for (int j = 0; j < 4; ++j)
#pragma unroll
          for (int rr = 0; rr < 4; ++rr) {
            int row = wrow + i * 16 + quad * 4 + rr;
            int col = (j * 16 + l15) ^ (((row >> 2) & 1) << 4);  // bank rotate
            float v = acc[i][j][rr] + bias[j];
            Cls[row * 64 + col] = v > 0.f ? v : 0.f;
          }
    }
    __syncthreads();
#pragma unroll
    for (int i = 0; i < 8; ++i) {
      int ch = t + i * 256;           // 128 rows x 16 chunks of 4 cols
      int row = ch >> 4, cc = ch & 15;
      int m = m0 + row;
      if (m >= M) continue;
      int scc = cc ^ (((row >> 2) & 1) << 2);
      float4v v = *(const float4v*)(Cls + row * 64 + scc * 4);
      int n = n0 + h * 64 + cc * 4;
      if (mode == 1) {
        size_t idx = base + (size_t)m * HDIM + n;
        if (f32) {
          *(float4v*)((float*)out + idx) = v;
        } else {
          uint2 u; u.x = pk2(v[0], v[1]); u.y = pk2(v[2], v[3]);
          *(uint2*)((unsigned short*)out + idx) = u;
        }
      } else {
        int orig = ridx[m];
        size_t idx = base + (size_t)orig * HDIM + n;
        float d0, d1, d2, d3;
        if (f32) {
          float4v w = *(const float4v*)((const float*)out + idx);
          d0 = w[0] - v[0]; d1 = w[1] - v[1]; d2 = w[2] - v[2]; d3 = w[3] - v[3];
        } else {
          uint2 u = *(const uint2*)((const unsigned short*)out + idx);
          d0 = __uint_as_float(u.x << 16) - v[0];
          d1 = __uint_as_float(u.x & 0xffff0000u) - v[1];
          d2 = __uint_as_float(u.y << 16) - v[2];
          d3 = __uint_as_float(u.y & 0xffff0000u) - v[3];
        }
        cpart += d0 * d0 + d1 * d1 + d2 * d2 + d3 * d3;
      }
    }
  }
  if (mode == 2) {
    cpart = wave_reduce(cpart);
    if (lane == 0) atomicAdd(&parts[(wg * 4 + wave) & 2047], cpart);
  }
}

// ---------------- loss ----------------
__global__ __launch_bounds__(256) void loss_final(const float* __restrict__ parts,
                                                  const int* __restrict__ cd,
                                                  const int* __restrict__ ct,
                                                  void* __restrict__ out, size_t off,
                                                  const int* __restrict__ flag) {
  float a = 0.f, b = 0.f;
  for (int i = threadIdx.x; i < 2048; i += 256) { a += parts[i]; b += parts[2048 + i]; }
  a = wave_reduce(a);
  b = wave_reduce(b);
  __shared__ float ra[4], rb[4];
  if ((threadIdx.x & 63) == 0) { ra[threadIdx.x >> 6] = a; rb[threadIdx.x >> 6] = b; }
  __syncthreads();
  if (threadIdx.x == 0) {
    float sd = ra[0] + ra[1] + ra[2] + ra[3];
    float st = rb[0] + rb[1] + rb[2] + rb[3];
    float loss = sd / ((float)cd[0] * (float)HDIM + 1e-16f)
               + st / ((float)ct[0] * (float)HDIM + 1e-16f);
    stx(out, off, flag[0], loss);
  }
}

// ---------------- host ----------------

extern "C" void kernel_launch(void* const* d_in, const int* in_sizes, int n_in,
                              void* d_out, int out_size, void* d_ws, size_t ws_size,
                              hipStream_t stream) {
  const void* drug_x    = d_in[0];
  const void* target_x  = d_in[1];
  const int* dd_src = (const int*)d_in[2];
  const int* dd_dst = (const int*)d_in[3];
  const int* dt_src = (const int*)d_in[4];
  const int* dt_dst = (const int*)d_in[5];
  const int* tt_src = (const int*)d_in[6];
  const int* tt_dst = (const int*)d_in[7];
  const int* drug_mask   = (const int*)d_in[8];
  const int* target_mask = (const int*)d_in[9];
  const void* mask_drug   = d_in[10];
  const void* mask_target = d_in[11];
  const void* Wsrc_dd = d_in[12]; const void* Wdst_dd = d_in[13];
  const void* asrc_dd = d_in[14]; const void* adst_dd = d_in[15];
  const void* b_dd    = d_in[16];
  const void* Wsrc_dt = d_in[17]; const void* Wdst_dt = d_in[18];
  const void* asrc_dt = d_in[19]; const void* adst_dt = d_in[20];
  const void* b_dt    = d_in[21];
  const void* Wsrc_rv = d_in[22]; const void* Wdst_rv = d_in[23];
  const void* asrc_rv = d_in[24]; const void* adst_rv = d_in[25];
  const void* b_rv    = d_in[26];
  const void* Wsrc_tt = d_in[27]; const void* Wdst_tt = d_in[28];
  const void* asrc_tt = d_in[29]; const void* adst_tt = d_in[30];
  const void* b_tt    = d_in[31];

  char* p = (char*)d_ws;
  auto alloc = [&](size_t bytes) -> void* {
    void* r = (void*)p;
    p += (bytes + 255) & ~(size_t)255;
    return r;
  };
  const size_t PAD = (size_t)BM * KPA * 2;  // tile-overrun slack for gemm staging
  unsigned short* Ad    = (unsigned short*)alloc((size_t)ND * KPD * 2);
  unsigned short* At    = (unsigned short*)alloc((size_t)NT * KPT * 2);
  unsigned short* aggd1 = (unsigned short*)alloc((size_t)ND * KPA * 2 + PAD);
  unsigned short* aggd2 = (unsigned short*)alloc((size_t)ND * KPA * 2 + PAD);
  unsigned short* aggt1 = (unsigned short*)alloc((size_t)NT * KPA * 2 + PAD);
  unsigned short* aggt2 = (unsigned short*)alloc((size_t)NT * KPA * 2 + PAD);
  unsigned short* BdW   = (unsigned short*)alloc((size_t)HDIM * KPA * 2);
  unsigned short* BtW   = (unsigned short*)alloc((size_t)HDIM * KPA * 2);
  float* dvec1 = (float*)alloc((size_t)ND * 4 * 4);   // L1 {es_dd, ed_dd, ed_rv, es_dt}
  float* tvec1 = (float*)alloc((size_t)NT * 4 * 4);   // L1 {es_rv, ed_dt, es_tt, ed_tt}
  int* rp_dd = (int*)alloc((size_t)(ND + 1) * 4);
  int* rp_rv = (int*)alloc((size_t)(ND + 1) * 4);
  int* rp_dt = (int*)alloc((size_t)(NT + 1) * 4);
  int* rp_tt = (int*)alloc((size_t)(NT + 1) * 4);
  int* ei_dd = (int*)alloc((size_t)(EDD + ND) * 4);
  int* ei_rv = (int*)alloc((size_t)EDT * 4);
  int* ei_dt = (int*)alloc((size_t)EDT * 4);
  int* ei_tt = (int*)alloc((size_t)(ETT + NT) * 4);
  // zero-block: cnt4 | fill4 | parts (one zeroing launch)
  const int ZN = 4 * (ND + NT) + 4096;
  int* zblock = (int*)alloc((size_t)ZN * 4);
  int* cnt_dd = zblock;
  int* cnt_rv = cnt_dd + ND;
  int* cnt_dt = cnt_rv + ND;
  int* cnt_tt = cnt_dt + NT;
  int* f_dd   = cnt_tt + NT;
  int* f_rv   = f_dd + ND;
  int* f_dt   = f_rv + ND;
  int* f_tt   = f_dt + NT;
  float* parts = (float*)(f_tt + NT);
  int* cidxD = (int*)alloc((size_t)(ND + 1) * 4);
  int* cidxT = (int*)alloc((size_t)(NT + 1) * 4);
  int* ridxD = (int*)alloc((size_t)ND * 4);
  int* ridxT = (int*)alloc((size_t)NT * 4);
  float* vaD = (float*)alloc((size_t)4 * FD * 4);
  float* vaT = (float*)alloc((size_t)4 * FT * 4);
  float* tokscal = (float*)alloc(64);
  int*   flag  = (int*)alloc(256);

  // 1) dtype sniff + zero counters/fills/parts
  sniff<<<1, 256, 0, stream>>>(drug_x, flag);
  zero_i32<<<(ZN + 255) / 256, 256, 0, stream>>>(zblock, ZN);

  // 2) va vectors (one launch) + token dots
  {
    int waves = 4 * FD + 4 * FT;
    wa_dot8<<<(waves * 64 + 255) / 256, 256, 0, stream>>>(
        Wsrc_dd, Wdst_dd, Wdst_rv, Wsrc_dt, Wsrc_rv, Wdst_dt, Wsrc_tt, Wdst_tt,
        asrc_dd, adst_dd, adst_rv, asrc_dt, asrc_rv, adst_dt, asrc_tt, adst_tt,
        vaD, vaT, flag);
    tok_dots<<<1, 512, 0, stream>>>(mask_drug, mask_target, vaD, vaT, tokscal, flag);
  }

  // 3) pack both concat weights in one launch
  {
    long long tb = 2 * ((long long)HDIM * KPA / 4);
    pack_bTa2<<<(int)((tb + 255) / 256), 256, 0, stream>>>(Wsrc_dd, Wsrc_rv, BdW,
                                                           Wsrc_dt, Wsrc_tt, BtW, flag);
  }

  // 4) CSR build + mask compaction (batched)
  {
    int total = (EDD + ND) + EDT + EDT + (ETT + NT);
    count4<<<(total + 255) / 256, 256, 0, stream>>>(dd_dst, dt_src, dt_dst, tt_dst,
                                                    cnt_dd, cnt_rv, cnt_dt, cnt_tt);
    scan6<<<6, 256, 0, stream>>>(cnt_dd, ND, rp_dd, cnt_rv, ND, rp_rv,
                                 cnt_dt, NT, rp_dt, cnt_tt, NT, rp_tt,
                                 drug_mask, ND, cidxD, target_mask, NT, cidxT);
    ridx2<<<(ND + NT + 255) / 256, 256, 0, stream>>>(drug_mask, cidxD, ridxD,
                                                     target_mask, cidxT, ridxT);
    fill4<<<(total + 255) / 256, 256, 0, stream>>>(dd_src, dd_dst, dt_src, dt_dst,
                                                   tt_src, tt_dst,
                                                   rp_dd, f_dd, ei_dd, rp_rv, f_rv, ei_rv,
                                                   rp_dt, f_dt, ei_dt, rp_tt, f_tt, ei_tt);
  }

  // 5) fused pack + es/ed dots (x read once, both node types)
  pack_rowdot<<<((ND + NT) * 64 + 255) / 256, 256, 0, stream>>>(
      drug_x, target_x, vaD, vaT, Ad, At, dvec1, tvec1, flag);

  // 6) merged dual-layer gather (both dst node types in one launch)
  gat_agg2<<<(ND + NT + 3) / 4, 256, 0, stream>>>(
      Ad, At, drug_mask, target_mask, mask_drug, mask_target, tokscal,
      rp_dd, ei_dd, dvec1 + 0, dvec1 + 1,
      rp_rv, ei_rv, tvec1 + 0, dvec1 + 2,
      cidxD, aggd1, aggd2,
      rp_dt, ei_dt, dvec1 + 3, tvec1 + 1,
      rp_tt, ei_tt, tvec1 + 2, tvec1 + 3,
      cidxT, aggt1, aggt2, flag);

  size_t baseT = (size_t)ND * HDIM;
  size_t baseL = baseT + (size_t)NT * HDIM;

  // 7) fused output GEMMs (layer1 stores; layer2 compact rows -> fused loss)
  const int NWG = 6 * (MTD + MTT);
  gemm2<<<NWG, 256, 0, stream>>>(
      aggd1, BdW, b_dd, b_rv, ND, nullptr, nullptr, 0ULL, parts,
      aggt1, BtW, b_dt, b_tt, NT, nullptr, nullptr, (unsigned long long)baseT, parts,
      MTD, NWG, d_out, 1, flag);
  gemm2<<<NWG, 256, 0, stream>>>(
      aggd2, BdW, b_dd, b_rv, ND, cidxD + ND, ridxD, 0ULL, parts,
      aggt2, BtW, b_dt, b_tt, NT, cidxT + NT, ridxT, (unsigned long long)baseT, parts + 2048,
      MTD, NWG, d_out, 2, flag);

  loss_final<<<1, 256, 0, stream>>>(parts, cidxD + ND, cidxT + NT, d_out, baseL, flag);
}

// Round 8
// 888.974 us; speedup vs baseline: 1.0634x; 1.0328x over previous
//
#include <hip/hip_runtime.h>
#include <hip/hip_bf16.h>

#define ND 30000
#define NT 15000
#define FD 200
#define FT 570
#define HDIM 768
#define EDD 300000
#define EDT 400000
#define ETT 200000

#define KPD 256   // FD padded to x64 (gather rel1 row: 512B)
#define KPT 576   // FT padded to x64 (gather rel2 row: 1152B)
#define KPA 832   // agg K = KPD + KPT (concat), GEMM K dim

#define BM 128
#define BN 128
#define GBK 32
#define KTILES (KPA / GBK)         // 26
#define MTD ((ND + BM - 1) / BM)   // 235
#define MTT ((NT + BM - 1) / BM)   // 118

// fused-kernel block ranges
#define TOT_EDGE ((EDD + ND) + EDT + EDT + (ETT + NT))      // 1,345,000
#define NB_CNT ((TOT_EDGE + 255) / 256)                     // 5254
#define NB_WA (((4 * FD + 4 * FT) * 64 + 255) / 256)        // 770
#define NB_PB ((2 * HDIM * KPA / 4 + 255) / 256)            // 1248
#define NB_RIDX ((ND + NT + 255) / 256)                     // 176
#define NB_PRD (((ND + NT) * 64 + 255) / 256)               // 11250

typedef __attribute__((ext_vector_type(8))) short short8;
typedef __attribute__((ext_vector_type(4))) float float4v;

// ---------------- dtype-adaptive load/store ----------------
// flag[0]: 0 = harness float tensors are bf16, 1 = fp32.

__device__ __forceinline__ float ldx(const void* p, size_t i, int f32) {
  return f32 ? ((const float*)p)[i]
             : __bfloat162float(((const __hip_bfloat16*)p)[i]);
}
__device__ __forceinline__ void stx(void* p, size_t i, int f32, float v) {
  if (f32) ((float*)p)[i] = v;
  else     ((__hip_bfloat16*)p)[i] = __float2bfloat16(v);
}
__device__ __forceinline__ float b2f(unsigned short u) {
  return __uint_as_float(((unsigned)u) << 16);
}
__device__ __forceinline__ unsigned short f2b(float f) {
  __hip_bfloat16 h = __float2bfloat16(f);
  return *(unsigned short*)&h;
}
__device__ __forceinline__ unsigned pk2(float a, float b) {
  return (unsigned)f2b(a) | ((unsigned)f2b(b) << 16);
}

__device__ __forceinline__ float wave_reduce(float v) {
#pragma unroll
  for (int off = 32; off > 0; off >>= 1) v += __shfl_xor(v, off, 64);
  return v;
}

// ---------------- fused init: sniff (block 0) || zero (rest) ----------------
__global__ __launch_bounds__(256) void init_k(const void* __restrict__ x,
                                              int* __restrict__ flag,
                                              int* __restrict__ zp, int zn) {
  if (blockIdx.x == 0) {
    int t = threadIdx.x;
    float cnt = 0.f;
    for (int i = t; i < 8192; i += 256) {
      float v = __bfloat162float(((const __hip_bfloat16*)x)[i]);
      if (!(fabsf(v) < 100.f)) cnt += 1.f;  // true for NaN too
    }
    cnt = wave_reduce(cnt);
    __shared__ float red[4];
    if ((t & 63) == 0) red[t >> 6] = cnt;
    __syncthreads();
    if (t == 0) flag[0] = (red[0] + red[1] + red[2] + red[3] > 256.f) ? 1 : 0;
  } else {
    int i = (blockIdx.x - 1) * 256 + threadIdx.x;
    if (i < zn) zp[i] = 0;
  }
}

// -------- fused setup: count4 || wa_dot8 || pack_bTa2 --------
__global__ __launch_bounds__(256) void setup_k(
    // count4
    const int* __restrict__ dd_dst, const int* __restrict__ dt_src,
    const int* __restrict__ dt_dst, const int* __restrict__ tt_dst,
    int* __restrict__ c_dd, int* __restrict__ c_rv,
    int* __restrict__ c_dt, int* __restrict__ c_tt,
    // wa_dot8 (8 W, 8 a)
    const void* W0, const void* W1, const void* W2, const void* W3,
    const void* W4, const void* W5, const void* W6, const void* W7,
    const void* a0, const void* a1, const void* a2, const void* a3,
    const void* a4, const void* a5, const void* a6, const void* a7,
    float* __restrict__ vaD, float* __restrict__ vaT,
    // pack_bTa2
    const void* __restrict__ PW1a, const void* __restrict__ PW2a, unsigned short* __restrict__ Ba,
    const void* __restrict__ PW1b, const void* __restrict__ PW2b, unsigned short* __restrict__ Bb,
    const int* __restrict__ flag) {
  int b = blockIdx.x;
  if (b < NB_CNT) {
    // ---- count4 ----
    int i = b * 256 + threadIdx.x;
    if (i < EDD + ND) { int d = (i < EDD) ? dd_dst[i] : i - EDD; atomicAdd(&c_dd[d], 1); return; }
    i -= EDD + ND;
    if (i < EDT) { atomicAdd(&c_rv[dt_src[i]], 1); return; }
    i -= EDT;
    if (i < EDT) { atomicAdd(&c_dt[dt_dst[i]], 1); return; }
    i -= EDT;
    if (i < ETT + NT) { int d = (i < ETT) ? tt_dst[i] : i - ETT; atomicAdd(&c_tt[d], 1); }
    return;
  }
  b -= NB_CNT;
  if (b < NB_WA) {
    // ---- wa_dot8 ----
    const void* Ws[8] = {W0, W1, W2, W3, W4, W5, W6, W7};
    const void* as[8] = {a0, a1, a2, a3, a4, a5, a6, a7};
    int f32 = flag[0];
    int wid = (b * 256 + threadIdx.x) >> 6;
    int lane = threadIdx.x & 63;
    const void* W; const void* a; float* out; int k;
    if (wid < 4 * FD) {
      int q = wid / FD; k = wid - q * FD;
      W = Ws[q]; a = as[q]; out = vaD + q * FD + k;
    } else {
      int w2 = wid - 4 * FD;
      if (w2 >= 4 * FT) return;
      int q = w2 / FT; k = w2 - q * FT;
      W = Ws[4 + q]; a = as[4 + q]; out = vaT + q * FT + k;
    }
    float acc = 0.f;
    for (int h = lane; h < HDIM; h += 64)
      acc += ldx(W, (size_t)k * HDIM + h, f32) * ldx(a, h, f32);
    acc = wave_reduce(acc);
    if (lane == 0) *out = acc;
    return;
  }
  b -= NB_WA;
  {
    // ---- pack_bTa2 ----
    int f32 = flag[0];
    long long one = (long long)HDIM * KPA / 4;
    long long gid = (long long)b * 256 + threadIdx.x;
    if (gid >= 2 * one) return;
    const void* Wp1; const void* Wp2; unsigned short* Bout;
    if (gid < one) { Wp1 = PW1a; Wp2 = PW2a; Bout = Ba; }
    else { Wp1 = PW1b; Wp2 = PW2b; Bout = Bb; gid -= one; }
    long long e0 = gid * 4;
    int n = (int)(e0 / KPA);
    int k = (int)(e0 % KPA);
    ushort4 o;
    unsigned short r[4];
#pragma unroll
    for (int c = 0; c < 4; ++c) {
      int kk = k + c;
      float f = 0.f;
      if (kk < 256) {
        if (kk < FD) f = ldx(Wp1, (size_t)kk * HDIM + n, f32);
      } else {
        int k2 = kk - 256;
        if (k2 < FT) f = ldx(Wp2, (size_t)k2 * HDIM + n, f32);
      }
      r[c] = f2b(f);
    }
    o.x = r[0]; o.y = r[1]; o.z = r[2]; o.w = r[3];
    *(ushort4*)(Bout + e0) = o;
  }
}

// -------- fused scan_tok: 6 scans (blocks 0-5) || tok_dots (block 6) --------
// ts layout {D0,D1,T0,D2, D3,T1,T2,T3}
__global__ __launch_bounds__(256) void scan_tok_k(
    const int* __restrict__ a0, int n0, int* __restrict__ o0,
    const int* __restrict__ a1, int n1, int* __restrict__ o1,
    const int* __restrict__ a2, int n2, int* __restrict__ o2,
    const int* __restrict__ a3, int n3, int* __restrict__ o3,
    const int* __restrict__ a4, int n4, int* __restrict__ o4,
    const int* __restrict__ a5, int n5, int* __restrict__ o5,
    const void* __restrict__ tok1, const void* __restrict__ tok2,
    const float* __restrict__ vaD, const float* __restrict__ vaT,
    float* __restrict__ ts, const int* __restrict__ flag) {
  __shared__ int part[256];
  if (blockIdx.x < 6) {
    const int* a; int n; int* o;
    switch (blockIdx.x) {
      case 0: a = a0; n = n0; o = o0; break;
      case 1: a = a1; n = n1; o = o1; break;
      case 2: a = a2; n = n2; o = o2; break;
      case 3: a = a3; n = n3; o = o3; break;
      case 4: a = a4; n = n4; o = o4; break;
      default: a = a5; n = n5; o = o5; break;
    }
    int t = threadIdx.x;
    int strip = (n + 255) / 256;
    int lo = min(t * strip, n), hi = min(lo + strip, n);
    int s = 0;
    for (int i = lo; i < hi; ++i) s += a[i];
    part[t] = s;
    __syncthreads();
    if (t == 0) {
      int run = 0;
      for (int i = 0; i < 256; ++i) { int v = part[i]; part[i] = run; run += v; }
    }
    __syncthreads();
    int run = part[t];
    for (int i = lo; i < hi; ++i) { o[i] = run; run += a[i]; }
    if (hi == n) o[n] = run;
  } else {
    // tok_dots: wave w (0..3) does FD-dot w and FT-dot w
    int w = threadIdx.x >> 6, lane = threadIdx.x & 63;
    int f32 = flag[0];
    const int mapD[4] = {0, 1, 3, 4};
    const int mapT[4] = {2, 5, 6, 7};
    float acc = 0.f;
    for (int k = lane; k < FD; k += 64) acc += ldx(tok1, k, f32) * vaD[w * FD + k];
    acc = wave_reduce(acc);
    if (lane == 0) ts[mapD[w]] = acc;
    acc = 0.f;
    for (int k = lane; k < FT; k += 64) acc += ldx(tok2, k, f32) * vaT[w * FT + k];
    acc = wave_reduce(acc);
    if (lane == 0) ts[mapT[w]] = acc;
  }
}

// -------- fused build: fill4 || ridx2 || pack_rowdot --------
__global__ __launch_bounds__(256) void build_k(
    // fill4
    const int* __restrict__ dd_src, const int* __restrict__ dd_dst,
    const int* __restrict__ dt_src, const int* __restrict__ dt_dst,
    const int* __restrict__ tt_src, const int* __restrict__ tt_dst,
    const int* __restrict__ rp_dd, int* __restrict__ f_dd, int* __restrict__ ei_dd,
    const int* __restrict__ rp_rv, int* __restrict__ f_rv, int* __restrict__ ei_rv,
    const int* __restrict__ rp_dt, int* __restrict__ f_dt, int* __restrict__ ei_dt,
    const int* __restrict__ rp_tt, int* __restrict__ f_tt, int* __restrict__ ei_tt,
    // ridx2
    const int* __restrict__ mD, const int* __restrict__ cD, int* __restrict__ rD,
    const int* __restrict__ mT, const int* __restrict__ cT, int* __restrict__ rT,
    // pack_rowdot
    const void* __restrict__ xD, const void* __restrict__ xT,
    const float* __restrict__ vaD, const float* __restrict__ vaT,
    unsigned short* __restrict__ Ad, unsigned short* __restrict__ At,
    float* __restrict__ dvec, float* __restrict__ tvec,
    const int* __restrict__ flag) {
  int b = blockIdx.x;
  if (b < NB_CNT) {
    // ---- fill4 ----
    int i = b * 256 + threadIdx.x;
    if (i < EDD + ND) {
      int s, d;
      if (i < EDD) { s = dd_src[i]; d = dd_dst[i]; } else { s = d = i - EDD; }
      ei_dd[rp_dd[d] + atomicAdd(&f_dd[d], 1)] = s;
      return;
    }
    i -= EDD + ND;
    if (i < EDT) {
      int d = dt_src[i], s = dt_dst[i];
      ei_rv[rp_rv[d] + atomicAdd(&f_rv[d], 1)] = s;
      return;
    }
    i -= EDT;
    if (i < EDT) {
      int d = dt_dst[i], s = dt_src[i];
      ei_dt[rp_dt[d] + atomicAdd(&f_dt[d], 1)] = s;
      return;
    }
    i -= EDT;
    if (i < ETT + NT) {
      int s, d;
      if (i < ETT) { s = tt_src[i]; d = tt_dst[i]; } else { s = d = i - ETT; }
      ei_tt[rp_tt[d] + atomicAdd(&f_tt[d], 1)] = s;
    }
    return;
  }
  b -= NB_CNT;
  if (b < NB_RIDX) {
    // ---- ridx2 ----
    int i = b * 256 + threadIdx.x;
    if (i < ND) { if (mD[i] != 0) rD[cD[i]] = i; return; }
    i -= ND;
    if (i < NT) { if (mT[i] != 0) rT[cT[i]] = i; }
    return;
  }
  b -= NB_RIDX;
  {
    // ---- pack_rowdot ----
    int wid = (b * 256 + threadIdx.x) >> 6;
    int lane = threadIdx.x & 63;
    int f32 = flag[0];
    const void* x; const float* va; unsigned short* Aout; float* outv; int K, Kp, row;
    if (wid < ND) { x = xD; va = vaD; Aout = Ad; outv = dvec; K = FD; Kp = KPD; row = wid; }
    else if (wid < ND + NT) { x = xT; va = vaT; Aout = At; outv = tvec; K = FT; Kp = KPT; row = wid - ND; }
    else return;
    float s0 = 0.f, s1 = 0.f, s2 = 0.f, s3 = 0.f;
    for (int it = 0; it * 256 < Kp; ++it) {
      int base = 4 * lane + it * 256;
      if (base >= Kp) continue;
      ushort4 o;
      unsigned short r[4];
      float fv[4];
#pragma unroll
      for (int c = 0; c < 4; ++c) {
        int kk = base + c;
        float f = (kk < K) ? ldx(x, (size_t)row * K + kk, f32) : 0.f;
        fv[c] = f;
        r[c] = f2b(f);
      }
      o.x = r[0]; o.y = r[1]; o.z = r[2]; o.w = r[3];
      *(ushort4*)(Aout + (size_t)row * Kp + base) = o;
#pragma unroll
      for (int c = 0; c < 4; ++c) {
        int kk = base + c;
        if (kk < K) {
          s0 += fv[c] * va[kk];
          s1 += fv[c] * va[K + kk];
          s2 += fv[c] * va[2 * K + kk];
          s3 += fv[c] * va[3 * K + kk];
        }
      }
    }
    s0 = wave_reduce(s0); s1 = wave_reduce(s1);
    s2 = wave_reduce(s2); s3 = wave_reduce(s3);
    if (lane == 0) {
      float* o = outv + (size_t)row * 4;
      o[0] = s0; o[1] = s1; o[2] = s2; o[3] = s3;
    }
  }
}

// ---------------- fused dual-layer GAT aggregation, BOTH node types ----------------
__device__ __forceinline__ void fma4(float* acc, uint2 A, float al) {
  unsigned w;
  w = A.x; acc[0] += al * __uint_as_float(w << 16); acc[1] += al * __uint_as_float(w & 0xffff0000u);
  w = A.y; acc[2] += al * __uint_as_float(w << 16); acc[3] += al * __uint_as_float(w & 0xffff0000u);
}

__device__ __forceinline__ float lrexp(float v) {
  v = (v >= 0.f) ? v : 0.2f * v;
  return __expf(v);
}

__global__ __launch_bounds__(256) void gat_agg2(
    // common sources
    const unsigned short* __restrict__ A1, const unsigned short* __restrict__ A2,
    const int* __restrict__ msk1, const int* __restrict__ msk2,
    const void* __restrict__ tok1, const void* __restrict__ tok2,
    const float* __restrict__ tokscal,
    // drug-dst problem
    const int* __restrict__ rpD1, const int* __restrict__ eiD1,
    const float* __restrict__ esD1, const float* __restrict__ edD1,
    const int* __restrict__ rpD2, const int* __restrict__ eiD2,
    const float* __restrict__ esD2, const float* __restrict__ edD2,
    const int* __restrict__ cidxD,
    unsigned short* __restrict__ aggd1, unsigned short* __restrict__ aggd2,
    // target-dst problem
    const int* __restrict__ rpT1, const int* __restrict__ eiT1,
    const float* __restrict__ esT1, const float* __restrict__ edT1,
    const int* __restrict__ rpT2, const int* __restrict__ eiT2,
    const float* __restrict__ esT2, const float* __restrict__ edT2,
    const int* __restrict__ cidxT,
    unsigned short* __restrict__ aggt1, unsigned short* __restrict__ aggt2,
    const int* __restrict__ flag) {
  int gwid = (blockIdx.x * 256 + threadIdx.x) >> 6;
  int lane = threadIdx.x & 63;
  if (gwid >= ND + NT) return;
  int f32 = flag[0];

  const int *rp1, *ei1, *rp2, *ei2, *cidx;
  const float *es1, *ed1, *es2, *ed2, *ts;
  const int* mdst;
  unsigned short *agg1, *agg2;
  int wid;
  if (gwid < ND) {
    wid = gwid; mdst = msk1;
    rp1 = rpD1; ei1 = eiD1; es1 = esD1; ed1 = edD1;
    rp2 = rpD2; ei2 = eiD2; es2 = esD2; ed2 = edD2;
    cidx = cidxD; agg1 = aggd1; agg2 = aggd2; ts = tokscal;
  } else {
    wid = gwid - ND; mdst = msk2;
    rp1 = rpT1; ei1 = eiT1; es1 = esT1; ed1 = edT1;
    rp2 = rpT2; ei2 = eiT2; es2 = esT2; ed2 = edT2;
    cidx = cidxT; agg1 = aggt1; agg2 = aggt2; ts = tokscal + 4;
  }

  bool need2 = (mdst[wid] != 0);  // wave-uniform
  float ac1[13], ac2[13];
#pragma unroll
  for (int c = 0; c < 13; ++c) { ac1[c] = 0.f; ac2[c] = 0.f; }

  // ---------------- rel1: src rows from A1 [*, KPD] ----------------
  {
    float tes = ts[0], ted = ts[1];
    int lo = rp1[wid], hi = rp1[wid + 1];
    float edA = ed1[4 * (size_t)wid];
    float s1 = 0.f, s2 = 0.f;
    for (int e = lo + lane; e < hi; e += 64) {
      int sn = ei1[e];
      float ev = es1[4 * (size_t)sn];
      s1 += lrexp(ev + edA);
      if (need2) {
        float e2 = (msk1[sn] != 0) ? tes : ev;
        s2 += lrexp(e2 + ted);
      }
    }
    s1 = wave_reduce(s1);
    float i1 = 1.f / (s1 + 1e-16f), i2 = 0.f;
    if (need2) { s2 = wave_reduce(s2); i2 = 1.f / (s2 + 1e-16f); }
    float wt = 0.f;
    int pn = (lo < hi) ? ei1[lo] : 0;
    for (int e = lo; e < hi; ++e) {
      int sn = __builtin_amdgcn_readfirstlane(pn);
      if (e + 1 < hi) pn = ei1[e + 1];
      uint2 rv = *(const uint2*)(A1 + (size_t)sn * KPD + 4 * lane);
      float ev = es1[4 * (size_t)sn];
      fma4(ac1, rv, lrexp(ev + edA) * i1);
      if (need2) {
        if (msk1[sn] != 0) wt += lrexp(tes + ted) * i2;
        else fma4(ac2, rv, lrexp(ev + ted) * i2);
      }
    }
    if (need2) {
#pragma unroll
      for (int c = 0; c < 4; ++c) {
        int col = 4 * lane + c;
        float tv = (col < FD) ? ldx(tok1, col, f32) : 0.f;
        ac2[c] += wt * tv;
      }
    }
  }

  // ---------------- rel2: src rows from A2 [*, KPT] ----------------
  {
    float tes = ts[2], ted = ts[3];
    int lo = rp2[wid], hi = rp2[wid + 1];
    float edA = ed2[4 * (size_t)wid];
    float s1 = 0.f, s2 = 0.f;
    for (int e = lo + lane; e < hi; e += 64) {
      int sn = ei2[e];
      float ev = es2[4 * (size_t)sn];
      s1 += lrexp(ev + edA);
      if (need2) {
        float e2 = (msk2[sn] != 0) ? tes : ev;
        s2 += lrexp(e2 + ted);
      }
    }
    s1 = wave_reduce(s1);
    float i1 = 1.f / (s1 + 1e-16f), i2 = 0.f;
    if (need2) { s2 = wave_reduce(s2); i2 = 1.f / (s2 + 1e-16f); }
    float wt = 0.f;
    int pn = (lo < hi) ? ei2[lo] : 0;
    for (int e = lo; e < hi; ++e) {
      int sn = __builtin_amdgcn_readfirstlane(pn);
      if (e + 1 < hi) pn = ei2[e + 1];
      const unsigned short* row = A2 + (size_t)sn * KPT;
      uint2 ra = *(const uint2*)(row + 4 * lane);
      uint2 rb = *(const uint2*)(row + 256 + 4 * lane);
      unsigned short rc = row[512 + lane];
      float ev = es2[4 * (size_t)sn];
      float a1 = lrexp(ev + edA) * i1;
      fma4(ac1 + 4, ra, a1);
      fma4(ac1 + 8, rb, a1);
      ac1[12] += a1 * b2f(rc);
      if (need2) {
        if (msk2[sn] != 0) {
          wt += lrexp(tes + ted) * i2;
        } else {
          float a2 = lrexp(ev + ted) * i2;
          fma4(ac2 + 4, ra, a2);
          fma4(ac2 + 8, rb, a2);
          ac2[12] += a2 * b2f(rc);
        }
      }
    }
    if (need2) {
#pragma unroll
      for (int c = 0; c < 4; ++c) {
        int colA = 4 * lane + c;
        int colB = 256 + 4 * lane + c;
        ac2[4 + c] += wt * ldx(tok2, colA, f32);
        ac2[8 + c] += wt * ldx(tok2, colB, f32);
      }
      int colC = 512 + lane;
      ac2[12] += wt * ((colC < FT) ? ldx(tok2, colC, f32) : 0.f);
    }
  }

  // ---------------- store agg rows (bf16) ----------------
  unsigned short* o1 = agg1 + (size_t)wid * KPA;
  uint2 u;
  u.x = pk2(ac1[0], ac1[1]);  u.y = pk2(ac1[2], ac1[3]);  *(uint2*)(o1 + 4 * lane) = u;
  u.x = pk2(ac1[4], ac1[5]);  u.y = pk2(ac1[6], ac1[7]);  *(uint2*)(o1 + 256 + 4 * lane) = u;
  u.x = pk2(ac1[8], ac1[9]);  u.y = pk2(ac1[10], ac1[11]); *(uint2*)(o1 + 512 + 4 * lane) = u;
  o1[768 + lane] = f2b(ac1[12]);
  if (need2) {
    unsigned short* o2 = agg2 + (size_t)cidx[wid] * KPA;
    u.x = pk2(ac2[0], ac2[1]);  u.y = pk2(ac2[2], ac2[3]);  *(uint2*)(o2 + 4 * lane) = u;
    u.x = pk2(ac2[4], ac2[5]);  u.y = pk2(ac2[6], ac2[7]);  *(uint2*)(o2 + 256 + 4 * lane) = u;
    u.x = pk2(ac2[8], ac2[9]);  u.y = pk2(ac2[10], ac2[11]); *(uint2*)(o2 + 512 + 4 * lane) = u;
    o2[768 + lane] = f2b(ac2[12]);
  }
}

// ---------------- fused dual-problem MFMA GEMM ----------------
// GBK=32, 48KB LDS: 3-buffer pipeline, distance-2 load landing (T3/T4):
// iter k: stage(b[k+2]) -> vmcnt(8) (tile k landed; k+1,k+2 in flight) ->
// s_barrier -> compute(b[k]) -> s_barrier.
// Safety: end-barrier guarantees all waves finished compute(k-1) before anyone
// stages b[(k+2)%3] == b[(k-1)%3]; per-wave vmcnt before start-barrier covers
// load visibility. XOR swizzle cs=(chunk&3)^((row>>1)&3) on both sides.
// Epilogue: two half-passes through LDS as 128x64 f32 (coalesced I/O).

__global__ __launch_bounds__(256) void gemm2(
    const unsigned short* __restrict__ A0, const unsigned short* __restrict__ B0,
    const void* __restrict__ c1_0, const void* __restrict__ c2_0,
    int M0s, const int* __restrict__ mc0, const int* __restrict__ rx0,
    unsigned long long base0, float* __restrict__ pp0,
    const unsigned short* __restrict__ A1, const unsigned short* __restrict__ B1,
    const void* __restrict__ c1_1, const void* __restrict__ c2_1,
    int M1s, const int* __restrict__ mc1, const int* __restrict__ rx1,
    unsigned long long base1, float* __restrict__ pp1,
    int mt0, int nwg, void* __restrict__ out, int mode,
    const int* __restrict__ flag) {
  __shared__ unsigned long long lds8[6144];  // 48KB: A 3x8KB + B 3x8KB
  unsigned short* ldsS = (unsigned short*)lds8;
  float* Cls = (float*)lds8;                 // epilogue: 128x64 f32 (32KB)

  // bijective XCD-chunk swizzle (m204)
  int b = blockIdx.x;
  int q = nwg >> 3, r = nwg & 7;
  int xcd = b & 7, pos = b >> 3;
  int wg = (xcd < r ? xcd * (q + 1) : r * (q + 1) + (xcd - r) * q) + pos;
  int prob = (wg >= 6 * mt0) ? 1 : 0;
  int rel = prob ? (wg - 6 * mt0) : wg;
  int mt = rel / 6, nt = rel - mt * 6;

  const unsigned short* A = prob ? A1 : A0;
  const unsigned short* Bt = prob ? B1 : B0;
  const void* c1 = prob ? c1_1 : c1_0;
  const void* c2 = prob ? c2_1 : c2_0;
  const int* mc = prob ? mc1 : mc0;
  const int* ridx = prob ? rx1 : rx0;
  size_t base = prob ? base1 : base0;
  float* parts = prob ? pp1 : pp0;
  int M = prob ? M1s : M0s;
  if (mc) M = *mc;
  int m0 = mt * BM;
  if (m0 >= M) return;
  int n0 = nt * BN;

  int t = threadIdx.x;
  int wave = t >> 6, lane = t & 63;
  int quad = lane >> 4, l15 = lane & 15;
  int wrow = (wave & 1) * 64, wcol = (wave >> 1) * 64;
  float4v acc[4][4];
#pragma unroll
  for (int i = 0; i < 4; ++i)
#pragma unroll
    for (int j = 0; j < 4; ++j) acc[i][j] = (float4v){0.f, 0.f, 0.f, 0.f};

  // stage one K-tile (128x32 each for A,B); 4 gload_lds per wave per stage
  auto stage = [&](int buf, int k0) {
#pragma unroll
    for (int i = 0; i < 2; ++i) {
      int chunk = (wave * 2 + i) * 64 + lane;
      int row = chunk >> 2;
      int cs = (chunk & 3) ^ ((row >> 1) & 3);
      const unsigned short* ga = A + (size_t)(m0 + row) * KPA + k0 + cs * 8;
      __builtin_amdgcn_global_load_lds(
          (const __attribute__((address_space(1))) unsigned int*)ga,
          (__attribute__((address_space(3))) unsigned int*)(ldsS + buf * 4096 + (wave * 2 + i) * 512),
          16, 0, 0);
      const unsigned short* gb = Bt + (size_t)(n0 + row) * KPA + k0 + cs * 8;
      __builtin_amdgcn_global_load_lds(
          (const __attribute__((address_space(1))) unsigned int*)gb,
          (__attribute__((address_space(3))) unsigned int*)(ldsS + 12288 + buf * 4096 + (wave * 2 + i) * 512),
          16, 0, 0);
    }
  };
  auto compute = [&](int buf) {
    short8 a[4], bfr[4];
#pragma unroll
    for (int i = 0; i < 4; ++i) {
      int rr = wrow + i * 16 + l15;
      a[i] = *(const short8*)(ldsS + buf * 4096 + rr * 32 + ((quad ^ ((rr >> 1) & 3)) << 3));
    }
#pragma unroll
    for (int j = 0; j < 4; ++j) {
      int rc = wcol + j * 16 + l15;
      bfr[j] = *(const short8*)(ldsS + 12288 + buf * 4096 + rc * 32 + ((quad ^ ((rc >> 1) & 3)) << 3));
    }
#pragma unroll
    for (int i = 0; i < 4; ++i)
#pragma unroll
      for (int j = 0; j < 4; ++j)
        acc[i][j] = __builtin_amdgcn_mfma_f32_16x16x32_bf16(a[i], bfr[j], acc[i][j], 0, 0, 0);
  };

  // ---- 3-buffer counted-vmcnt pipeline, distance-2 landing ----
  stage(0, 0);                      // tile 0: 4 loads in flight
  stage(1, GBK);                    // tile 1: 8 in flight
#pragma unroll 1
  for (int ks = 0; ks < KTILES - 2; ++ks) {
    stage((ks + 2) % 3, (ks + 2) * GBK);   // 12 in flight
    asm volatile("s_waitcnt vmcnt(8)" ::: "memory");  // tile ks landed
    __builtin_amdgcn_sched_barrier(0);
    __builtin_amdgcn_s_barrier();
    compute(ks % 3);
    __builtin_amdgcn_s_barrier();
  }
  asm volatile("s_waitcnt vmcnt(4)" ::: "memory");
  __builtin_amdgcn_sched_barrier(0);
  __builtin_amdgcn_s_barrier();
  compute((KTILES - 2) % 3);
  __builtin_amdgcn_s_barrier();
  asm volatile("s_waitcnt vmcnt(0)" ::: "memory");
  __builtin_amdgcn_sched_barrier(0);
  __builtin_amdgcn_s_barrier();
  compute((KTILES - 1) % 3);

  // ---------------- epilogue: two half-passes via 128x64 f32 LDS ----------------
  int f32 = flag[0];
  float bias[4];
#pragma unroll
  for (int j = 0; j < 4; ++j) {
    int n = n0 + wcol + j * 16 + l15;
    bias[j] = ldx(c1, n, f32) + ldx(c2, n, f32);
  }
  float cpart = 0.f;
#pragma unroll
  for (int h = 0; h < 2; ++h) {
    __syncthreads();   // staging reads (h=0) / prior half reads (h=1) complete
    if ((wave >> 1) == h) {  // this wave's cols live in half h
#pragma unroll
      for (int i = 0; i < 4; ++i)
#pragma unroll
        for (int j = 0; j < 4; ++j)
#pragma unroll
          for (int rr = 0; rr < 4; ++rr) {
            int row = wrow + i * 16 + quad * 4 + rr;
            int col = (j * 16 + l15) ^ (((row >> 2) & 1) << 4);  // bank rotate
            float v = acc[i][j][rr] + bias[j];
            Cls[row * 64 + col] = v > 0.f ? v : 0.f;
          }
    }
    __syncthreads();
#pragma unroll
    for (int i = 0; i < 8; ++i) {
      int ch = t + i * 256;           // 128 rows x 16 chunks of 4 cols
      int row = ch >> 4, cc = ch & 15;
      int m = m0 + row;
      if (m >= M) continue;
      int scc = cc ^ (((row >> 2) & 1) << 2);
      float4v v = *(const float4v*)(Cls + row * 64 + scc * 4);
      int n = n0 + h * 64 + cc * 4;
      if (mode == 1) {
        size_t idx = base + (size_t)m * HDIM + n;
        if (f32) {
          *(float4v*)((float*)out + idx) = v;
        } else {
          uint2 u; u.x = pk2(v[0], v[1]); u.y = pk2(v[2], v[3]);
          *(uint2*)((unsigned short*)out + idx) = u;
        }
      } else {
        int orig = ridx[m];
        size_t idx = base + (size_t)orig * HDIM + n;
        float d0, d1, d2, d3;
        if (f32) {
          float4v w = *(const float4v*)((const float*)out + idx);
          d0 = w[0] - v[0]; d1 = w[1] - v[1]; d2 = w[2] - v[2]; d3 = w[3] - v[3];
        } else {
          uint2 u = *(const uint2*)((const unsigned short*)out + idx);
          d0 = __uint_as_float(u.x << 16) - v[0];
          d1 = __uint_as_float(u.x & 0xffff0000u) - v[1];
          d2 = __uint_as_float(u.y << 16) - v[2];
          d3 = __uint_as_float(u.y & 0xffff0000u) - v[3];
        }
        cpart += d0 * d0 + d1 * d1 + d2 * d2 + d3 * d3;
      }
    }
  }
  if (mode == 2) {
    cpart = wave_reduce(cpart);
    if (lane == 0) atomicAdd(&parts[(wg * 4 + wave) & 2047], cpart);
  }
}

// ---------------- loss ----------------
__global__ __launch_bounds__(256) void loss_final(const float* __restrict__ parts,
                                                  const int* __restrict__ cd,
                                                  const int* __restrict__ ct,
                                                  void* __restrict__ out, size_t off,
                                                  const int* __restrict__ flag) {
  float a = 0.f, b = 0.f;
  for (int i = threadIdx.x; i < 2048; i += 256) { a += parts[i]; b += parts[2048 + i]; }
  a = wave_reduce(a);
  b = wave_reduce(b);
  __shared__ float ra[4], rb[4];
  if ((threadIdx.x & 63) == 0) { ra[threadIdx.x >> 6] = a; rb[threadIdx.x >> 6] = b; }
  __syncthreads();
  if (threadIdx.x == 0) {
    float sd = ra[0] + ra[1] + ra[2] + ra[3];
    float st = rb[0] + rb[1] + rb[2] + rb[3];
    float loss = sd / ((float)cd[0] * (float)HDIM + 1e-16f)
               + st / ((float)ct[0] * (float)HDIM + 1e-16f);
    stx(out, off, flag[0], loss);
  }
}

// ---------------- host ----------------

extern "C" void kernel_launch(void* const* d_in, const int* in_sizes, int n_in,
                              void* d_out, int out_size, void* d_ws, size_t ws_size,
                              hipStream_t stream) {
  const void* drug_x    = d_in[0];
  const void* target_x  = d_in[1];
  const int* dd_src = (const int*)d_in[2];
  const int* dd_dst = (const int*)d_in[3];
  const int* dt_src = (const int*)d_in[4];
  const int* dt_dst = (const int*)d_in[5];
  const int* tt_src = (const int*)d_in[6];
  const int* tt_dst = (const int*)d_in[7];
  const int* drug_mask   = (const int*)d_in[8];
  const int* target_mask = (const int*)d_in[9];
  const void* mask_drug   = d_in[10];
  const void* mask_target = d_in[11];
  const void* Wsrc_dd = d_in[12]; const void* Wdst_dd = d_in[13];
  const void* asrc_dd = d_in[14]; const void* adst_dd = d_in[15];
  const void* b_dd    = d_in[16];
  const void* Wsrc_dt = d_in[17]; const void* Wdst_dt = d_in[18];
  const void* asrc_dt = d_in[19]; const void* adst_dt = d_in[20];
  const void* b_dt    = d_in[21];
  const void* Wsrc_rv = d_in[22]; const void* Wdst_rv = d_in[23];
  const void* asrc_rv = d_in[24]; const void* adst_rv = d_in[25];
  const void* b_rv    = d_in[26];
  const void* Wsrc_tt = d_in[27]; const void* Wdst_tt = d_in[28];
  const void* asrc_tt = d_in[29]; const void* adst_tt = d_in[30];
  const void* b_tt    = d_in[31];

  char* p = (char*)d_ws;
  auto alloc = [&](size_t bytes) -> void* {
    void* r = (void*)p;
    p += (bytes + 255) & ~(size_t)255;
    return r;
  };
  const size_t PAD = (size_t)BM * KPA * 2;  // tile-overrun slack for gemm staging
  unsigned short* Ad    = (unsigned short*)alloc((size_t)ND * KPD * 2);
  unsigned short* At    = (unsigned short*)alloc((size_t)NT * KPT * 2);
  unsigned short* aggd1 = (unsigned short*)alloc((size_t)ND * KPA * 2 + PAD);
  unsigned short* aggd2 = (unsigned short*)alloc((size_t)ND * KPA * 2 + PAD);
  unsigned short* aggt1 = (unsigned short*)alloc((size_t)NT * KPA * 2 + PAD);
  unsigned short* aggt2 = (unsigned short*)alloc((size_t)NT * KPA * 2 + PAD);
  unsigned short* BdW   = (unsigned short*)alloc((size_t)HDIM * KPA * 2);
  unsigned short* BtW   = (unsigned short*)alloc((size_t)HDIM * KPA * 2);
  float* dvec1 = (float*)alloc((size_t)ND * 4 * 4);   // L1 {es_dd, ed_dd, ed_rv, es_dt}
  float* tvec1 = (float*)alloc((size_t)NT * 4 * 4);   // L1 {es_rv, ed_dt, es_tt, ed_tt}
  int* rp_dd = (int*)alloc((size_t)(ND + 1) * 4);
  int* rp_rv = (int*)alloc((size_t)(ND + 1) * 4);
  int* rp_dt = (int*)alloc((size_t)(NT + 1) * 4);
  int* rp_tt = (int*)alloc((size_t)(NT + 1) * 4);
  int* ei_dd = (int*)alloc((size_t)(EDD + ND) * 4);
  int* ei_rv = (int*)alloc((size_t)EDT * 4);
  int* ei_dt = (int*)alloc((size_t)EDT * 4);
  int* ei_tt = (int*)alloc((size_t)(ETT + NT) * 4);
  // zero-block: cnt4 | fill4 | parts (one zeroing pass inside init_k)
  const int ZN = 4 * (ND + NT) + 4096;
  int* zblock = (int*)alloc((size_t)ZN * 4);
  int* cnt_dd = zblock;
  int* cnt_rv = cnt_dd + ND;
  int* cnt_dt = cnt_rv + ND;
  int* cnt_tt = cnt_dt + NT;
  int* f_dd   = cnt_tt + NT;
  int* f_rv   = f_dd + ND;
  int* f_dt   = f_rv + ND;
  int* f_tt   = f_dt + NT;
  float* parts = (float*)(f_tt + NT);
  int* cidxD = (int*)alloc((size_t)(ND + 1) * 4);
  int* cidxT = (int*)alloc((size_t)(NT + 1) * 4);
  int* ridxD = (int*)alloc((size_t)ND * 4);
  int* ridxT = (int*)alloc((size_t)NT * 4);
  float* vaD = (float*)alloc((size_t)4 * FD * 4);
  float* vaT = (float*)alloc((size_t)4 * FT * 4);
  float* tokscal = (float*)alloc(64);
  int*   flag  = (int*)alloc(256);

  // 1) init: dtype sniff || zero counters/fills/parts
  init_k<<<1 + (ZN + 255) / 256, 256, 0, stream>>>(drug_x, flag, zblock, ZN);

  // 2) setup: count4 || wa_dot8 || pack_bTa2
  setup_k<<<NB_CNT + NB_WA + NB_PB, 256, 0, stream>>>(
      dd_dst, dt_src, dt_dst, tt_dst, cnt_dd, cnt_rv, cnt_dt, cnt_tt,
      Wsrc_dd, Wdst_dd, Wdst_rv, Wsrc_dt, Wsrc_rv, Wdst_dt, Wsrc_tt, Wdst_tt,
      asrc_dd, adst_dd, adst_rv, asrc_dt, asrc_rv, adst_dt, asrc_tt, adst_tt,
      vaD, vaT,
      Wsrc_dd, Wsrc_rv, BdW, Wsrc_dt, Wsrc_tt, BtW, flag);

  // 3) scan_tok: 6 exclusive scans || token dots
  scan_tok_k<<<7, 256, 0, stream>>>(
      cnt_dd, ND, rp_dd, cnt_rv, ND, rp_rv,
      cnt_dt, NT, rp_dt, cnt_tt, NT, rp_tt,
      drug_mask, ND, cidxD, target_mask, NT, cidxT,
      mask_drug, mask_target, vaD, vaT, tokscal, flag);

  // 4) build: fill4 || ridx2 || pack_rowdot
  build_k<<<NB_CNT + NB_RIDX + NB_PRD, 256, 0, stream>>>(
      dd_src, dd_dst, dt_src, dt_dst, tt_src, tt_dst,
      rp_dd, f_dd, ei_dd, rp_rv, f_rv, ei_rv,
      rp_dt, f_dt, ei_dt, rp_tt, f_tt, ei_tt,
      drug_mask, cidxD, ridxD, target_mask, cidxT, ridxT,
      drug_x, target_x, vaD, vaT, Ad, At, dvec1, tvec1, flag);

  // 5) merged dual-layer gather (both dst node types in one launch)
  gat_agg2<<<(ND + NT + 3) / 4, 256, 0, stream>>>(
      Ad, At, drug_mask, target_mask, mask_drug, mask_target, tokscal,
      rp_dd, ei_dd, dvec1 + 0, dvec1 + 1,
      rp_rv, ei_rv, tvec1 + 0, dvec1 + 2,
      cidxD, aggd1, aggd2,
      rp_dt, ei_dt, dvec1 + 3, tvec1 + 1,
      rp_tt, ei_tt, tvec1 + 2, tvec1 + 3,
      cidxT, aggt1, aggt2, flag);

  size_t baseT = (size_t)ND * HDIM;
  size_t baseL = baseT + (size_t)NT * HDIM;

  // 6) fused output GEMMs (layer1 stores; layer2 compact rows -> fused loss)
  const int NWG = 6 * (MTD + MTT);
  gemm2<<<NWG, 256, 0, stream>>>(
      aggd1, BdW, b_dd, b_rv, ND, nullptr, nullptr, 0ULL, parts,
      aggt1, BtW, b_dt, b_tt, NT, nullptr, nullptr, (unsigned long long)baseT, parts,
      MTD, NWG, d_out, 1, flag);
  gemm2<<<NWG, 256, 0, stream>>>(
      aggd2, BdW, b_dd, b_rv, ND, cidxD + ND, ridxD, 0ULL, parts,
      aggt2, BtW, b_dt, b_tt, NT, cidxT + NT, ridxT, (unsigned long long)baseT, parts + 2048,
      MTD, NWG, d_out, 2, flag);

  loss_final<<<1, 256, 0, stream>>>(parts, cidxD + ND, cidxT + NT, d_out, baseL, flag);
}